// Round 3
// baseline (912.472 us; speedup 1.0000x reference)
//
#include <hip/hip_runtime.h>
#include <stdint.h>

#define N_NODES 100000
#define N_EDGES 1000000

typedef unsigned short u16;
typedef unsigned int u32;
typedef __attribute__((ext_vector_type(8))) short bshort8;
typedef __attribute__((ext_vector_type(4))) float f32x4;

__device__ __forceinline__ float bf2f(u16 u){ union{float f; u32 i;} x; x.i=((u32)u)<<16; return x.f; }
__device__ __forceinline__ u16 f2bf(float f){ union{float f; u32 i;} x; x.f=f; u32 r = x.i + 0x7FFFu + ((x.i>>16)&1u); return (u16)(r>>16); }
__device__ __forceinline__ float sigf(float x){ return 1.0f/(1.0f+__expf(-x)); }
__device__ __forceinline__ float tanhfast(float x){ return 1.0f - 2.0f/(__expf(2.0f*x)+1.0f); }

// ---------------- dtype detector: f32 buffers read as u16 have garbage mantissa halves ----------------
__global__ void k_detect(const u16* __restrict__ x, int* flagp){
    __shared__ int cnt;
    if(threadIdx.x == 0) cnt = 0;
    __syncthreads();
    int c = 0;
    for(int i = threadIdx.x; i < 2048; i += 256){
        int e = (x[i] >> 7) & 0xFF;
        if(e >= 0x90) c++;              // |val| >= 2^17: impossible for sane bf16 data
    }
    atomicAdd(&cnt, c);
    __syncthreads();
    if(threadIdx.x == 0) flagp[0] = (cnt > 64) ? 1 : 0;   // 1 = f32, 0 = bf16
}

// canonical f32 table: element offsets (compile-time)
#define CX    0
#define CW1   800000
#define CB1   800512
#define CW2   800576
#define CB2   804672
#define CEMB  804736
#define CWIH  808832
#define CWHH  821120
#define CBIH  833408
#define CBHH  833600
#define CL1W  833792
#define CL1B  841984
#define CLTW  842048
#define CLTB  850240
#define CLFW  850304
#define CLFB  850560
#define CTOT  850562

__device__ __forceinline__ float ldany(const void* p, int i, int fl){
    return fl ? ((const float*)p)[i] : bf2f(((const u16*)p)[i]);
}

__global__ void k_convert(const int* __restrict__ flagp,
                          const void* x, const void* w1, const void* b1, const void* w2,
                          const void* b2, const void* emb, const void* wih, const void* whh,
                          const void* bih, const void* bhh, const void* l1w, const void* l1b,
                          const void* ltw, const void* ltb, const void* lfw, const void* lfb,
                          float* __restrict__ canon){
    int i = blockIdx.x*256 + threadIdx.x;
    if(i >= CTOT) return;
    int fl = *flagp;
    const void* p; int off;
    if     (i < CW1 ){ p = x;   off = i;        }
    else if(i < CB1 ){ p = w1;  off = i - CW1;  }
    else if(i < CW2 ){ p = b1;  off = i - CB1;  }
    else if(i < CB2 ){ p = w2;  off = i - CW2;  }
    else if(i < CEMB){ p = b2;  off = i - CB2;  }
    else if(i < CWIH){ p = emb; off = i - CEMB; }
    else if(i < CWHH){ p = wih; off = i - CWIH; }
    else if(i < CBIH){ p = whh; off = i - CWHH; }
    else if(i < CBHH){ p = bih; off = i - CBIH; }
    else if(i < CL1W){ p = bhh; off = i - CBHH; }
    else if(i < CL1B){ p = l1w; off = i - CL1W; }
    else if(i < CLTW){ p = l1b; off = i - CL1B; }
    else if(i < CLTB){ p = ltw; off = i - CLTW; }
    else if(i < CLFW){ p = ltb; off = i - CLTB; }
    else if(i < CLFB){ p = lfw; off = i - CLFW; }
    else             { p = lfb; off = i - CLFB; }
    float v = ldany(p, off, fl);
    canon[i] = (v == v && fabsf(v) < 1e30f) ? v : 0.f;   // NaN/Inf clamp (diagnostic guard)
}

// ---------------- degree / norm ----------------
__global__ void k_deginit(float* deg){
    int i = blockIdx.x*256 + threadIdx.x;
    if(i < N_NODES) deg[i] = 1.0f;               // self loop
}
__global__ void k_degcount(const int* ei, float* deg){
    int e = blockIdx.x*256 + threadIdx.x;
    if(e < N_EDGES) atomicAdd(&deg[ei[N_EDGES + e]], 1.0f);
}
__global__ void k_dinv(float* deg){
    int i = blockIdx.x*256 + threadIdx.x;
    if(i < N_NODES) deg[i] = rsqrtf(deg[i]);
}

// ---------------- conv1: src = (x @ W1) * dinv   (f32) ----------------
__global__ void k_t1s(const float* __restrict__ cx, const float* __restrict__ cw1,
                      const float* __restrict__ dinv, float* __restrict__ src){
    __shared__ float w[512];
    int t = threadIdx.x;
    w[t]       = cw1[t];
    w[t + 256] = cw1[t + 256];
    __syncthreads();
    int i = blockIdx.x*256 + t;      // grid exactly N*64/256
    int n = i >> 6, f = i & 63;
    const float* xr = cx + n*8;
    float acc = 0.f;
    #pragma unroll
    for(int k = 0; k < 8; k++) acc += xr[k] * w[k*64 + f];
    src[i] = acc * dinv[n];
}

// ---------------- scatter-add: agg[dst] += src[s]  (f32) ----------------
__global__ void k_scatter(const int* __restrict__ ei, const float* __restrict__ src,
                          float* __restrict__ agg){
    int i = blockIdx.x*256 + threadIdx.x;   // grid exactly E*64/256
    int e = i >> 6, f = i & 63;
    int s = ei[e], d = ei[N_EDGES + e];
    atomicAdd(&agg[d*64 + f], src[s*64 + f]);
}

// ---------------- epilogue: h = bf16(relu(dinv*(agg+src)+b)) ----------------
__global__ void k_gcn_ep(const float* __restrict__ agg, const float* __restrict__ src,
                         const float* __restrict__ dinv, const float* __restrict__ b,
                         u16* __restrict__ h){
    int i = blockIdx.x*256 + threadIdx.x;   // exact
    int n = i >> 6, f = i & 63;
    float v = dinv[n]*(agg[i] + src[i]) + b[f];
    h[i] = f2bf(fmaxf(v, 0.f));
}

// ---------------- pack B matrix (f32 canon -> bf16 MFMA fragment order) ----------------
// B[k][n] = src[k*ldk + n*ldn]; frag (kt,nt): lane L elem j -> B[kt*32+(L>>4)*8+j][nt*16+(L&15)]
__global__ void k_packb(const float* __restrict__ src, u16* __restrict__ dst,
                        int K, int N, int ldk, int ldn){
    int i = blockIdx.x*256 + threadIdx.x;
    if(i >= K*N) return;
    int k = i / N, n = i % N;
    int kt = k >> 5, kk = k & 31, q = kk >> 3, j = kk & 7;
    int nt = n >> 4, nn = n & 15;
    int KT = K >> 5;
    dst[(((nt*KT + kt)*64) + (q*16 + nn))*8 + j] = f2bf(src[k*ldk + n*ldn]);
}

// ---------------- gi table: gi[v][g] = b_ih[g] + sum_f w_ih[g][f]*embed[v][f] ----------------
__global__ void k_gitab(const float* __restrict__ emb, const float* __restrict__ wih,
                        const float* __restrict__ bih, float* __restrict__ giT){
    int i = blockIdx.x*256 + threadIdx.x;
    if(i >= 64*192) return;
    int v = i / 192, g = i % 192;
    float acc = bih[g];
    const float* wr = wih + g*64;
    const float* er = emb + v*64;
    for(int f = 0; f < 64; f++) acc += wr[f] * er[f];
    giT[i] = acc;
}

// ---------------- conv2 GEMM: src = (h1 @ W2) * dinv   (bf16 in, f32 out) ----------------
__global__ __launch_bounds__(256, 4)
void k_conv2(const u16* __restrict__ h, const u16* __restrict__ w2p,
             const float* __restrict__ dinv, float* __restrict__ src){
    int wv = threadIdx.x >> 6, lane = threadIdx.x & 63;
    int g = blockIdx.x*4 + wv;
    if(g >= N_NODES/16) return;
    int q = lane >> 4, m = lane & 15, col = m;
    bshort8 a0 = *(const bshort8*)(h + (g*16 + m)*64 + q*8);
    bshort8 a1 = *(const bshort8*)(h + (g*16 + m)*64 + 32 + q*8);
    f32x4 acc[4];
    #pragma unroll
    for(int nt = 0; nt < 4; nt++){
        f32x4 c = {0.f,0.f,0.f,0.f};
        c = __builtin_amdgcn_mfma_f32_16x16x32_bf16(a0, *(const bshort8*)(w2p + ((nt*2+0)*64 + lane)*8), c, 0,0,0);
        c = __builtin_amdgcn_mfma_f32_16x16x32_bf16(a1, *(const bshort8*)(w2p + ((nt*2+1)*64 + lane)*8), c, 0,0,0);
        acc[nt] = c;
    }
    #pragma unroll
    for(int nt = 0; nt < 4; nt++)
        #pragma unroll
        for(int r = 0; r < 4; r++){
            int node = g*16 + q*4 + r;
            src[node*64 + nt*16 + col] = acc[nt][r] * dinv[node];
        }
}

// ---------------- GRU: wave per 16 nodes, 10 steps, gi via table lookup ----------------
__global__ __launch_bounds__(256, 2)
void k_gru(const int* __restrict__ xt, const u16* __restrict__ whhp,
           const float* __restrict__ giT, const float* __restrict__ bhh,
           u16* __restrict__ txt){
    __shared__ __align__(16) u16 hsh[4][16][72];   // +8 pad
    int wv = threadIdx.x >> 6, lane = threadIdx.x & 63;
    int q = lane >> 4, m = lane & 15, col = m;
    int g = blockIdx.x*4 + wv;
    bool active = g < (N_NODES/16);
    int nb = active ? g*16 : 0;

    bshort8 wf[24];
    #pragma unroll
    for(int i = 0; i < 24; i++) wf[i] = *(const bshort8*)(whhp + (i*64 + lane)*8);
    float bhh_[12];
    #pragma unroll
    for(int i = 0; i < 12; i++) bhh_[i] = bhh[i*16 + col];

    float hc[4][4];
    #pragma unroll
    for(int t = 0; t < 4; t++)
        #pragma unroll
        for(int r = 0; r < 4; r++) hc[t][r] = 0.f;

    for(int s = 0; s < 10; s++){
        #pragma unroll
        for(int t = 0; t < 4; t++)
            #pragma unroll
            for(int r = 0; r < 4; r++)
                hsh[wv][q*4 + r][t*16 + col] = f2bf(hc[t][r]);
        __syncthreads();
        bshort8 a0 = *(const bshort8*)&hsh[wv][m][q*8];
        bshort8 a1 = *(const bshort8*)&hsh[wv][m][32 + q*8];
        __syncthreads();

        int tok[4];
        #pragma unroll
        for(int r = 0; r < 4; r++) tok[r] = xt[(nb + q*4 + r)*10 + s] & 63;

        f32x4 acc[12];
        #pragma unroll
        for(int nt = 0; nt < 12; nt++){
            f32x4 c = {0.f,0.f,0.f,0.f};
            c = __builtin_amdgcn_mfma_f32_16x16x32_bf16(a0, wf[nt*2],     c, 0,0,0);
            c = __builtin_amdgcn_mfma_f32_16x16x32_bf16(a1, wf[nt*2 + 1], c, 0,0,0);
            acc[nt] = c;
        }
        #pragma unroll
        for(int t = 0; t < 4; t++)
            #pragma unroll
            for(int r = 0; r < 4; r++){
                const float* gp = giT + tok[r]*192;
                float gir = gp[t*16 + col], giz = gp[64 + t*16 + col], gin = gp[128 + t*16 + col];
                float rr = sigf(gir + acc[t][r]     + bhh_[t]);
                float zz = sigf(giz + acc[4+t][r]   + bhh_[4+t]);
                float nn = tanhfast(gin + rr*(acc[8+t][r] + bhh_[8+t]));
                hc[t][r] = (1.f - zz)*nn + zz*hc[t][r];
            }
    }
    if(active){
        #pragma unroll
        for(int t = 0; t < 4; t++)
            #pragma unroll
            for(int r = 0; r < 4; r++)
                txt[(nb + q*4 + r)*64 + t*16 + col] = f2bf(hc[t][r]);
    }
}

// ---------------- edge MLP + final + log_softmax: wave per 16 edges ----------------
__global__ __launch_bounds__(256, 2)
void k_edge(const int* __restrict__ ei, const u16* __restrict__ h2, const u16* __restrict__ txt,
            const u16* __restrict__ l1p, const u16* __restrict__ ltp,
            const float* __restrict__ b1, const float* __restrict__ bt,
            const float* __restrict__ wfin, const float* __restrict__ bfin,
            const int* __restrict__ flagp, void* __restrict__ out){
    int lane = threadIdx.x & 63;
    int q = lane >> 4, m = lane & 15, col = m;
    int wgid = (blockIdx.x*256 + threadIdx.x) >> 6;
    int nw = (gridDim.x*256) >> 6;
    int fl = *flagp;

    bshort8 wa[16], wb[16];
    #pragma unroll
    for(int i = 0; i < 16; i++){
        wa[i] = *(const bshort8*)(l1p + (i*64 + lane)*8);
        wb[i] = *(const bshort8*)(ltp + (i*64 + lane)*8);
    }
    float b1c[4], btc[4], wfp[2][4], wft[2][4];
    #pragma unroll
    for(int t = 0; t < 4; t++){
        b1c[t] = b1[t*16 + col];
        btc[t] = bt[t*16 + col];
        wfp[0][t] = wfin[t*16 + col];        wfp[1][t] = wfin[128 + t*16 + col];
        wft[0][t] = wfin[64 + t*16 + col];   wft[1][t] = wfin[128 + 64 + t*16 + col];
    }
    float bf0 = bfin[0], bf1 = bfin[1];

    for(int g = wgid; g < N_EDGES/16; g += nw){
        int e = g*16 + m;
        int s = ei[e], d = ei[N_EDGES + e];
        bshort8 a0 = *(const bshort8*)(h2 + s*64 + q*8);
        bshort8 a1 = *(const bshort8*)(h2 + s*64 + 32 + q*8);
        bshort8 a2 = *(const bshort8*)(h2 + d*64 + q*8);
        bshort8 a3 = *(const bshort8*)(h2 + d*64 + 32 + q*8);
        f32x4 p[4];
        #pragma unroll
        for(int nt = 0; nt < 4; nt++){
            f32x4 c = {0.f,0.f,0.f,0.f};
            c = __builtin_amdgcn_mfma_f32_16x16x32_bf16(a0, wa[nt*4+0], c, 0,0,0);
            c = __builtin_amdgcn_mfma_f32_16x16x32_bf16(a1, wa[nt*4+1], c, 0,0,0);
            c = __builtin_amdgcn_mfma_f32_16x16x32_bf16(a2, wa[nt*4+2], c, 0,0,0);
            c = __builtin_amdgcn_mfma_f32_16x16x32_bf16(a3, wa[nt*4+3], c, 0,0,0);
            p[nt] = c;
        }
        bshort8 c0 = *(const bshort8*)(txt + s*64 + q*8);
        bshort8 c1 = *(const bshort8*)(txt + s*64 + 32 + q*8);
        bshort8 c2 = *(const bshort8*)(txt + d*64 + q*8);
        bshort8 c3 = *(const bshort8*)(txt + d*64 + 32 + q*8);
        f32x4 pt[4];
        #pragma unroll
        for(int nt = 0; nt < 4; nt++){
            f32x4 c = {0.f,0.f,0.f,0.f};
            c = __builtin_amdgcn_mfma_f32_16x16x32_bf16(c0, wb[nt*4+0], c, 0,0,0);
            c = __builtin_amdgcn_mfma_f32_16x16x32_bf16(c1, wb[nt*4+1], c, 0,0,0);
            c = __builtin_amdgcn_mfma_f32_16x16x32_bf16(c2, wb[nt*4+2], c, 0,0,0);
            c = __builtin_amdgcn_mfma_f32_16x16x32_bf16(c3, wb[nt*4+3], c, 0,0,0);
            pt[nt] = c;
        }
        float l0[4], l1[4];
        #pragma unroll
        for(int r = 0; r < 4; r++){
            float s0 = 0.f, s1 = 0.f;
            #pragma unroll
            for(int t = 0; t < 4; t++){
                float xp = fmaxf(p[t][r]  + b1c[t], 0.f);
                float xq = fmaxf(pt[t][r] + btc[t], 0.f);
                s0 += xp*wfp[0][t] + xq*wft[0][t];
                s1 += xp*wfp[1][t] + xq*wft[1][t];
            }
            l0[r] = s0; l1[r] = s1;
        }
        #pragma unroll
        for(int r = 0; r < 4; r++)
            #pragma unroll
            for(int msk = 1; msk < 16; msk <<= 1){
                l0[r] += __shfl_xor(l0[r], msk, 64);
                l1[r] += __shfl_xor(l1[r], msk, 64);
            }
        if(m == 0){
            #pragma unroll
            for(int r = 0; r < 4; r++){
                float a = l0[r] + bf0, b = l1[r] + bf1;
                float mx = fmaxf(a, b);
                float lse = mx + __logf(__expf(a - mx) + __expf(b - mx));
                int oi = g*16 + q*4 + r;
                if(fl){
                    float2 v; v.x = a - lse; v.y = b - lse;
                    ((float2*)out)[oi] = v;
                }else{
                    u32 pack = (u32)f2bf(a - lse) | ((u32)f2bf(b - lse) << 16);
                    ((u32*)out)[oi] = pack;
                }
            }
        }
    }
}

// ---------------- workspace layout (~68 MB) ----------------
static const size_t O_FLAG = 0;          // int flag
static const size_t O_CANON= 4096;       // CTOT f32 = 3,402,248 B
static const size_t O_GIT  = 3407872;    // 64*192 f32 = 49,152
static const size_t O_W2P  = 3457024;    // 8,192
static const size_t O_WHHP = 3465216;    // 24,576
static const size_t O_L1P  = 3489792;    // 16,384
static const size_t O_LTP  = 3506176;    // 16,384
static const size_t O_DINV = 3522560;    // 400,000
static const size_t O_SRC  = 3923968;    // N*64 f32 = 25,600,000
static const size_t O_H    = 29523968;   // N*64 bf16 = 12,800,000
static const size_t O_AGG  = 42323968;   // N*64 f32 = 25,600,000 (txt bf16 overlays after ep2)
// end = 67,923,968

extern "C" void kernel_launch(void* const* d_in, const int* in_sizes, int n_in,
                              void* d_out, int out_size, void* d_ws, size_t ws_size,
                              hipStream_t stream){
    const void* x    = d_in[0];
    const int*  ei   = (const int*)d_in[1];
    const int*  xt   = (const int*)d_in[2];

    char* ws = (char*)d_ws;
    int*   flagp = (int*)(ws + O_FLAG);
    float* canon = (float*)(ws + O_CANON);
    float* giT   = (float*)(ws + O_GIT);
    u16*   w2p   = (u16*)(ws + O_W2P);
    u16*   whhp  = (u16*)(ws + O_WHHP);
    u16*   l1p   = (u16*)(ws + O_L1P);
    u16*   ltp   = (u16*)(ws + O_LTP);
    float* dinv  = (float*)(ws + O_DINV);
    float* src   = (float*)(ws + O_SRC);
    u16*   hbuf  = (u16*)(ws + O_H);
    float* agg   = (float*)(ws + O_AGG);
    u16*   txt   = (u16*)(ws + O_AGG);   // overlay (agg dead after ep2)

    // dtype detect + canonicalize all float inputs to f32
    k_detect<<<1, 256, 0, stream>>>((const u16*)x, flagp);
    k_convert<<<(CTOT+255)/256, 256, 0, stream>>>(flagp,
        x, d_in[3], d_in[4], d_in[5], d_in[6], d_in[7], d_in[8], d_in[9],
        d_in[10], d_in[11], d_in[12], d_in[13], d_in[14], d_in[15], d_in[16], d_in[17],
        canon);

    const float* cx   = canon + CX;
    const float* cw1  = canon + CW1;
    const float* cb1  = canon + CB1;
    const float* cw2  = canon + CW2;
    const float* cb2  = canon + CB2;
    const float* cemb = canon + CEMB;
    const float* cwih = canon + CWIH;
    const float* cwhh = canon + CWHH;
    const float* cbih = canon + CBIH;
    const float* cbhh = canon + CBHH;
    const float* cl1w = canon + CL1W;
    const float* cl1b = canon + CL1B;
    const float* cltw = canon + CLTW;
    const float* cltb = canon + CLTB;
    const float* clfw = canon + CLFW;
    const float* clfb = canon + CLFB;

    // norm
    hipMemsetAsync(agg, 0, (size_t)N_NODES*64*4, stream);
    k_deginit<<<(N_NODES+255)/256, 256, 0, stream>>>(dinv);
    k_degcount<<<(N_EDGES+255)/256, 256, 0, stream>>>(ei, dinv);
    k_dinv<<<(N_NODES+255)/256, 256, 0, stream>>>(dinv);

    // weight packing + gi table (tiny)
    k_packb<<<(64*64+255)/256, 256, 0, stream>>>(cw2, w2p, 64, 64, 64, 1);
    k_packb<<<(64*192+255)/256, 256, 0, stream>>>(cwhh, whhp, 64, 192, 1, 64);
    k_packb<<<(128*64+255)/256, 256, 0, stream>>>(cl1w, l1p, 128, 64, 1, 128);
    k_packb<<<(128*64+255)/256, 256, 0, stream>>>(cltw, ltp, 128, 64, 1, 128);
    k_gitab<<<(64*192+255)/256, 256, 0, stream>>>(cemb, cwih, cbih, giT);

    // GCN layer 1
    k_t1s<<<N_NODES*64/256, 256, 0, stream>>>(cx, cw1, dinv, src);
    k_scatter<<<N_EDGES/4, 256, 0, stream>>>(ei, src, agg);
    k_gcn_ep<<<N_NODES*64/256, 256, 0, stream>>>(agg, src, dinv, cb1, hbuf);

    // GCN layer 2
    k_conv2<<<(N_NODES/16 + 3)/4, 256, 0, stream>>>(hbuf, w2p, dinv, src);
    hipMemsetAsync(agg, 0, (size_t)N_NODES*64*4, stream);
    k_scatter<<<N_EDGES/4, 256, 0, stream>>>(ei, src, agg);
    k_gcn_ep<<<N_NODES*64/256, 256, 0, stream>>>(agg, src, dinv, cb2, hbuf);

    // GRU over text (txt overlays agg, dead now)
    k_gru<<<(N_NODES/16 + 3)/4, 256, 0, stream>>>(xt, whhp, giT, cbhh, txt);

    // edge-pair MLPs + final + log_softmax
    k_edge<<<2048, 256, 0, stream>>>(ei, hbuf, txt, l1p, ltp, cl1b, cltb, clfw, clfb,
                                     flagp, d_out);
}

// Round 4
// 608.283 us; speedup vs baseline: 1.5001x; 1.5001x over previous
//
#include <hip/hip_runtime.h>
#include <stdint.h>

#define N_NODES 100000
#define N_EDGES 1000000
#define NBLK 391   // ceil(N_NODES/256)

typedef unsigned short u16;
typedef unsigned int u32;
typedef __attribute__((ext_vector_type(8))) short bshort8;
typedef __attribute__((ext_vector_type(4))) float f32x4;

__device__ __forceinline__ float bf2f(u16 u){ union{float f; u32 i;} x; x.i=((u32)u)<<16; return x.f; }
__device__ __forceinline__ u16 f2bf(float f){ union{float f; u32 i;} x; x.f=f; u32 r = x.i + 0x7FFFu + ((x.i>>16)&1u); return (u16)(r>>16); }
__device__ __forceinline__ float sigf(float x){ return 1.0f/(1.0f+__expf(-x)); }
__device__ __forceinline__ float tanhfast(float x){ return 1.0f - 2.0f/(__expf(2.0f*x)+1.0f); }

// ---------------- dtype detector (f32 vs bf16 device buffers) ----------------
__global__ void k_detect(const u16* __restrict__ x, int* flagp){
    __shared__ int cnt;
    if(threadIdx.x == 0) cnt = 0;
    __syncthreads();
    int c = 0;
    for(int i = threadIdx.x; i < 2048; i += 256){
        int e = (x[i] >> 7) & 0xFF;
        if(e >= 0x90) c++;
    }
    atomicAdd(&cnt, c);
    __syncthreads();
    if(threadIdx.x == 0) flagp[0] = (cnt > 64) ? 1 : 0;   // 1 = f32, 0 = bf16
}

// canonical f32 table offsets
#define CX    0
#define CW1   800000
#define CB1   800512
#define CW2   800576
#define CB2   804672
#define CEMB  804736
#define CWIH  808832
#define CWHH  821120
#define CBIH  833408
#define CBHH  833600
#define CL1W  833792
#define CL1B  841984
#define CLTW  842048
#define CLTB  850240
#define CLFW  850304
#define CLFB  850560
#define CTOT  850562

__device__ __forceinline__ float ldany(const void* p, int i, int fl){
    return fl ? ((const float*)p)[i] : bf2f(((const u16*)p)[i]);
}

__global__ void k_convert(const int* __restrict__ flagp,
                          const void* x, const void* w1, const void* b1, const void* w2,
                          const void* b2, const void* emb, const void* wih, const void* whh,
                          const void* bih, const void* bhh, const void* l1w, const void* l1b,
                          const void* ltw, const void* ltb, const void* lfw, const void* lfb,
                          float* __restrict__ canon){
    int i = blockIdx.x*256 + threadIdx.x;
    if(i >= CTOT) return;
    int fl = *flagp;
    const void* p; int off;
    if     (i < CW1 ){ p = x;   off = i;        }
    else if(i < CB1 ){ p = w1;  off = i - CW1;  }
    else if(i < CW2 ){ p = b1;  off = i - CB1;  }
    else if(i < CB2 ){ p = w2;  off = i - CW2;  }
    else if(i < CEMB){ p = b2;  off = i - CB2;  }
    else if(i < CWIH){ p = emb; off = i - CEMB; }
    else if(i < CWHH){ p = wih; off = i - CWIH; }
    else if(i < CBIH){ p = whh; off = i - CWHH; }
    else if(i < CBHH){ p = bih; off = i - CBIH; }
    else if(i < CL1W){ p = bhh; off = i - CBHH; }
    else if(i < CL1B){ p = l1w; off = i - CL1W; }
    else if(i < CLTW){ p = l1b; off = i - CL1B; }
    else if(i < CLTB){ p = ltw; off = i - CLTW; }
    else if(i < CLFW){ p = ltb; off = i - CLTB; }
    else if(i < CLFB){ p = lfw; off = i - CLFW; }
    else             { p = lfb; off = i - CLFB; }
    float v = ldany(p, off, fl);
    canon[i] = (v == v && fabsf(v) < 1e30f) ? v : 0.f;
}

// ---------------- CSR build: histogram -> scan -> fill ----------------
__global__ void k_hist(const int* __restrict__ ei, int* __restrict__ deg){
    int e = blockIdx.x*256 + threadIdx.x;
    if(e < N_EDGES) atomicAdd(&deg[ei[N_EDGES + e]], 1);
}
__global__ void k_scan1(const int* __restrict__ deg, int* __restrict__ rowptr,
                        int* __restrict__ bsum){
    __shared__ int sh[256];
    int tid = threadIdx.x;
    int i = blockIdx.x*256 + tid;
    int v = (i < N_NODES) ? deg[i] : 0;
    sh[tid] = v;
    __syncthreads();
    for(int off = 1; off < 256; off <<= 1){
        int t = (tid >= off) ? sh[tid - off] : 0;
        __syncthreads();
        sh[tid] += t;
        __syncthreads();
    }
    if(i < N_NODES) rowptr[i] = sh[tid] - v;     // exclusive within block
    if(tid == 255) bsum[blockIdx.x] = sh[255];
}
__global__ void k_scan2(int* __restrict__ bsum){
    __shared__ int sh[512];
    int tid = threadIdx.x;
    int v = (tid < NBLK) ? bsum[tid] : 0;
    sh[tid] = v;
    __syncthreads();
    for(int off = 1; off < 512; off <<= 1){
        int t = (tid >= off) ? sh[tid - off] : 0;
        __syncthreads();
        sh[tid] += t;
        __syncthreads();
    }
    if(tid < NBLK) bsum[tid] = sh[tid] - v;      // exclusive block offsets
}
__global__ void k_scan3(const int* __restrict__ deg, const int* __restrict__ bsum,
                        int* __restrict__ rowptr, int* __restrict__ cursor,
                        float* __restrict__ dinv){
    int i = blockIdx.x*256 + threadIdx.x;
    if(i < N_NODES){
        int r = rowptr[i] + bsum[i >> 8];
        rowptr[i] = r;
        cursor[i] = r;
        dinv[i] = rsqrtf((float)deg[i] + 1.0f);   // +1 self loop
    }
    if(i == 0) rowptr[N_NODES] = N_EDGES;
}
__global__ void k_fill(const int* __restrict__ ei, int* __restrict__ cursor,
                       int* __restrict__ el){
    int e = blockIdx.x*256 + threadIdx.x;
    if(e < N_EDGES){
        int s = ei[e], d = ei[N_EDGES + e];
        int pos = atomicAdd(&cursor[d], 1);
        el[pos] = s;
    }
}

// ---------------- conv1: src = (x @ W1) * dinv   (f32) ----------------
__global__ void k_t1s(const float* __restrict__ cx, const float* __restrict__ cw1,
                      const float* __restrict__ dinv, float* __restrict__ src){
    __shared__ float w[512];
    int t = threadIdx.x;
    w[t]       = cw1[t];
    w[t + 256] = cw1[t + 256];
    __syncthreads();
    int i = blockIdx.x*256 + t;      // grid exactly N*64/256
    int n = i >> 6, f = i & 63;
    const float* xr = cx + n*8;
    float acc = 0.f;
    #pragma unroll
    for(int k = 0; k < 8; k++) acc += xr[k] * w[k*64 + f];
    src[i] = acc * dinv[n];
}

// ---------------- fused gather + epilogue: h = bf16(relu(dinv*(sum in-rows + self) + b)) ----------------
__global__ __launch_bounds__(256)
void k_gather_ep(const int* __restrict__ rowptr, const int* __restrict__ el,
                 const float* __restrict__ src, const float* __restrict__ dinv,
                 const float* __restrict__ b, u16* __restrict__ h){
    int gid = blockIdx.x*256 + threadIdx.x;   // grid exactly N*64/256
    int node = gid >> 6, lane = gid & 63;
    int beg = rowptr[node], end = rowptr[node + 1];
    float acc = src[node*64 + lane];          // self loop (already dinv[n]-scaled)
    int i = beg;
    for(; i + 4 <= end; i += 4){
        int s0 = el[i], s1 = el[i+1], s2 = el[i+2], s3 = el[i+3];
        float a0 = src[s0*64 + lane];
        float a1 = src[s1*64 + lane];
        float a2 = src[s2*64 + lane];
        float a3 = src[s3*64 + lane];
        acc += a0; acc += a1; acc += a2; acc += a3;
    }
    for(; i < end; i++) acc += src[el[i]*64 + lane];
    h[node*64 + lane] = f2bf(fmaxf(dinv[node]*acc + b[lane], 0.f));
}

// ---------------- pack B matrix (f32 canon -> bf16 MFMA fragment order) ----------------
__global__ void k_packb(const float* __restrict__ src, u16* __restrict__ dst,
                        int K, int N, int ldk, int ldn){
    int i = blockIdx.x*256 + threadIdx.x;
    if(i >= K*N) return;
    int k = i / N, n = i % N;
    int kt = k >> 5, kk = k & 31, q = kk >> 3, j = kk & 7;
    int nt = n >> 4, nn = n & 15;
    int KT = K >> 5;
    dst[(((nt*KT + kt)*64) + (q*16 + nn))*8 + j] = f2bf(src[k*ldk + n*ldn]);
}

// ---------------- gi table ----------------
__global__ void k_gitab(const float* __restrict__ emb, const float* __restrict__ wih,
                        const float* __restrict__ bih, float* __restrict__ giT){
    int i = blockIdx.x*256 + threadIdx.x;
    if(i >= 64*192) return;
    int v = i / 192, g = i % 192;
    float acc = bih[g];
    const float* wr = wih + g*64;
    const float* er = emb + v*64;
    for(int f = 0; f < 64; f++) acc += wr[f] * er[f];
    giT[i] = acc;
}

// ---------------- conv2 GEMM: src = (h1 @ W2) * dinv ----------------
__global__ __launch_bounds__(256, 4)
void k_conv2(const u16* __restrict__ h, const u16* __restrict__ w2p,
             const float* __restrict__ dinv, float* __restrict__ src){
    int wv = threadIdx.x >> 6, lane = threadIdx.x & 63;
    int g = blockIdx.x*4 + wv;
    if(g >= N_NODES/16) return;
    int q = lane >> 4, m = lane & 15, col = m;
    bshort8 a0 = *(const bshort8*)(h + (g*16 + m)*64 + q*8);
    bshort8 a1 = *(const bshort8*)(h + (g*16 + m)*64 + 32 + q*8);
    f32x4 acc[4];
    #pragma unroll
    for(int nt = 0; nt < 4; nt++){
        f32x4 c = {0.f,0.f,0.f,0.f};
        c = __builtin_amdgcn_mfma_f32_16x16x32_bf16(a0, *(const bshort8*)(w2p + ((nt*2+0)*64 + lane)*8), c, 0,0,0);
        c = __builtin_amdgcn_mfma_f32_16x16x32_bf16(a1, *(const bshort8*)(w2p + ((nt*2+1)*64 + lane)*8), c, 0,0,0);
        acc[nt] = c;
    }
    #pragma unroll
    for(int nt = 0; nt < 4; nt++)
        #pragma unroll
        for(int r = 0; r < 4; r++){
            int node = g*16 + q*4 + r;
            src[node*64 + nt*16 + col] = acc[nt][r] * dinv[node];
        }
}

// ---------------- GRU ----------------
__global__ __launch_bounds__(256, 2)
void k_gru(const int* __restrict__ xt, const u16* __restrict__ whhp,
           const float* __restrict__ giT, const float* __restrict__ bhh,
           u16* __restrict__ txt){
    __shared__ __align__(16) u16 hsh[4][16][72];
    int wv = threadIdx.x >> 6, lane = threadIdx.x & 63;
    int q = lane >> 4, m = lane & 15, col = m;
    int g = blockIdx.x*4 + wv;
    bool active = g < (N_NODES/16);
    int nb = active ? g*16 : 0;

    bshort8 wf[24];
    #pragma unroll
    for(int i = 0; i < 24; i++) wf[i] = *(const bshort8*)(whhp + (i*64 + lane)*8);
    float bhh_[12];
    #pragma unroll
    for(int i = 0; i < 12; i++) bhh_[i] = bhh[i*16 + col];

    float hc[4][4];
    #pragma unroll
    for(int t = 0; t < 4; t++)
        #pragma unroll
        for(int r = 0; r < 4; r++) hc[t][r] = 0.f;

    for(int s = 0; s < 10; s++){
        #pragma unroll
        for(int t = 0; t < 4; t++)
            #pragma unroll
            for(int r = 0; r < 4; r++)
                hsh[wv][q*4 + r][t*16 + col] = f2bf(hc[t][r]);
        __syncthreads();
        bshort8 a0 = *(const bshort8*)&hsh[wv][m][q*8];
        bshort8 a1 = *(const bshort8*)&hsh[wv][m][32 + q*8];
        __syncthreads();

        int tok[4];
        #pragma unroll
        for(int r = 0; r < 4; r++) tok[r] = xt[(nb + q*4 + r)*10 + s] & 63;

        f32x4 acc[12];
        #pragma unroll
        for(int nt = 0; nt < 12; nt++){
            f32x4 c = {0.f,0.f,0.f,0.f};
            c = __builtin_amdgcn_mfma_f32_16x16x32_bf16(a0, wf[nt*2],     c, 0,0,0);
            c = __builtin_amdgcn_mfma_f32_16x16x32_bf16(a1, wf[nt*2 + 1], c, 0,0,0);
            acc[nt] = c;
        }
        #pragma unroll
        for(int t = 0; t < 4; t++)
            #pragma unroll
            for(int r = 0; r < 4; r++){
                const float* gp = giT + tok[r]*192;
                float gir = gp[t*16 + col], giz = gp[64 + t*16 + col], gin = gp[128 + t*16 + col];
                float rr = sigf(gir + acc[t][r]     + bhh_[t]);
                float zz = sigf(giz + acc[4+t][r]   + bhh_[4+t]);
                float nn = tanhfast(gin + rr*(acc[8+t][r] + bhh_[8+t]));
                hc[t][r] = (1.f - zz)*nn + zz*hc[t][r];
            }
    }
    if(active){
        #pragma unroll
        for(int t = 0; t < 4; t++)
            #pragma unroll
            for(int r = 0; r < 4; r++)
                txt[(nb + q*4 + r)*64 + t*16 + col] = f2bf(hc[t][r]);
    }
}

// ---------------- edge MLP + final + log_softmax ----------------
__global__ __launch_bounds__(256, 2)
void k_edge(const int* __restrict__ ei, const u16* __restrict__ h2, const u16* __restrict__ txt,
            const u16* __restrict__ l1p, const u16* __restrict__ ltp,
            const float* __restrict__ b1, const float* __restrict__ bt,
            const float* __restrict__ wfin, const float* __restrict__ bfin,
            const int* __restrict__ flagp, void* __restrict__ out){
    int lane = threadIdx.x & 63;
    int q = lane >> 4, m = lane & 15, col = m;
    int wgid = (blockIdx.x*256 + threadIdx.x) >> 6;
    int nw = (gridDim.x*256) >> 6;
    int fl = *flagp;

    bshort8 wa[16], wb[16];
    #pragma unroll
    for(int i = 0; i < 16; i++){
        wa[i] = *(const bshort8*)(l1p + (i*64 + lane)*8);
        wb[i] = *(const bshort8*)(ltp + (i*64 + lane)*8);
    }
    float b1c[4], btc[4], wfp[2][4], wft[2][4];
    #pragma unroll
    for(int t = 0; t < 4; t++){
        b1c[t] = b1[t*16 + col];
        btc[t] = bt[t*16 + col];
        wfp[0][t] = wfin[t*16 + col];        wfp[1][t] = wfin[128 + t*16 + col];
        wft[0][t] = wfin[64 + t*16 + col];   wft[1][t] = wfin[128 + 64 + t*16 + col];
    }
    float bf0 = bfin[0], bf1 = bfin[1];

    for(int g = wgid; g < N_EDGES/16; g += nw){
        int e = g*16 + m;
        int s = ei[e], d = ei[N_EDGES + e];
        bshort8 a0 = *(const bshort8*)(h2 + s*64 + q*8);
        bshort8 a1 = *(const bshort8*)(h2 + s*64 + 32 + q*8);
        bshort8 a2 = *(const bshort8*)(h2 + d*64 + q*8);
        bshort8 a3 = *(const bshort8*)(h2 + d*64 + 32 + q*8);
        f32x4 p[4];
        #pragma unroll
        for(int nt = 0; nt < 4; nt++){
            f32x4 c = {0.f,0.f,0.f,0.f};
            c = __builtin_amdgcn_mfma_f32_16x16x32_bf16(a0, wa[nt*4+0], c, 0,0,0);
            c = __builtin_amdgcn_mfma_f32_16x16x32_bf16(a1, wa[nt*4+1], c, 0,0,0);
            c = __builtin_amdgcn_mfma_f32_16x16x32_bf16(a2, wa[nt*4+2], c, 0,0,0);
            c = __builtin_amdgcn_mfma_f32_16x16x32_bf16(a3, wa[nt*4+3], c, 0,0,0);
            p[nt] = c;
        }
        bshort8 c0 = *(const bshort8*)(txt + s*64 + q*8);
        bshort8 c1 = *(const bshort8*)(txt + s*64 + 32 + q*8);
        bshort8 c2 = *(const bshort8*)(txt + d*64 + q*8);
        bshort8 c3 = *(const bshort8*)(txt + d*64 + 32 + q*8);
        f32x4 pt[4];
        #pragma unroll
        for(int nt = 0; nt < 4; nt++){
            f32x4 c = {0.f,0.f,0.f,0.f};
            c = __builtin_amdgcn_mfma_f32_16x16x32_bf16(c0, wb[nt*4+0], c, 0,0,0);
            c = __builtin_amdgcn_mfma_f32_16x16x32_bf16(c1, wb[nt*4+1], c, 0,0,0);
            c = __builtin_amdgcn_mfma_f32_16x16x32_bf16(c2, wb[nt*4+2], c, 0,0,0);
            c = __builtin_amdgcn_mfma_f32_16x16x32_bf16(c3, wb[nt*4+3], c, 0,0,0);
            pt[nt] = c;
        }
        float l0[4], l1[4];
        #pragma unroll
        for(int r = 0; r < 4; r++){
            float s0 = 0.f, s1 = 0.f;
            #pragma unroll
            for(int t = 0; t < 4; t++){
                float xp = fmaxf(p[t][r]  + b1c[t], 0.f);
                float xq = fmaxf(pt[t][r] + btc[t], 0.f);
                s0 += xp*wfp[0][t] + xq*wft[0][t];
                s1 += xp*wfp[1][t] + xq*wft[1][t];
            }
            l0[r] = s0; l1[r] = s1;
        }
        #pragma unroll
        for(int r = 0; r < 4; r++)
            #pragma unroll
            for(int msk = 1; msk < 16; msk <<= 1){
                l0[r] += __shfl_xor(l0[r], msk, 64);
                l1[r] += __shfl_xor(l1[r], msk, 64);
            }
        if(m == 0){
            #pragma unroll
            for(int r = 0; r < 4; r++){
                float a = l0[r] + bf0, b = l1[r] + bf1;
                float mx = fmaxf(a, b);
                float lse = mx + __logf(__expf(a - mx) + __expf(b - mx));
                int oi = g*16 + q*4 + r;
                if(fl){
                    float2 v; v.x = a - lse; v.y = b - lse;
                    ((float2*)out)[oi] = v;
                }else{
                    u32 pack = (u32)f2bf(a - lse) | ((u32)f2bf(b - lse) << 16);
                    ((u32*)out)[oi] = pack;
                }
            }
        }
    }
}

// ---------------- workspace layout (~60.3 MB) ----------------
static const size_t O_FLAG   = 0;
static const size_t O_CANON  = 4096;       // 3,402,248 B
static const size_t O_GIT    = 3407872;    // 49,152
static const size_t O_W2P    = 3457024;    // 8,192
static const size_t O_WHHP   = 3465216;    // 24,576
static const size_t O_L1P    = 3489792;    // 16,384
static const size_t O_LTP    = 3506176;    // 16,384
static const size_t O_DINV   = 3522560;    // 400,000
static const size_t O_DEG    = 3922560;    // 400,000
static const size_t O_ROWPTR = 4322560;    // 400,128 (N+1 ints, padded)
static const size_t O_CURSOR = 4722688;    // 400,000
static const size_t O_BSUM   = 5122688;    // 2,048
static const size_t O_EL     = 5124736;    // 4,000,000
static const size_t O_SRC    = 9124864;    // 25,600,000
static const size_t O_H      = 34724864;   // 12,800,000
static const size_t O_TXT    = 47524864;   // 12,800,000
// end = 60,324,864

extern "C" void kernel_launch(void* const* d_in, const int* in_sizes, int n_in,
                              void* d_out, int out_size, void* d_ws, size_t ws_size,
                              hipStream_t stream){
    const void* x    = d_in[0];
    const int*  ei   = (const int*)d_in[1];
    const int*  xt   = (const int*)d_in[2];

    char* ws = (char*)d_ws;
    int*   flagp  = (int*)(ws + O_FLAG);
    float* canon  = (float*)(ws + O_CANON);
    float* giT    = (float*)(ws + O_GIT);
    u16*   w2p    = (u16*)(ws + O_W2P);
    u16*   whhp   = (u16*)(ws + O_WHHP);
    u16*   l1p    = (u16*)(ws + O_L1P);
    u16*   ltp    = (u16*)(ws + O_LTP);
    float* dinv   = (float*)(ws + O_DINV);
    int*   deg    = (int*)(ws + O_DEG);
    int*   rowptr = (int*)(ws + O_ROWPTR);
    int*   cursor = (int*)(ws + O_CURSOR);
    int*   bsum   = (int*)(ws + O_BSUM);
    int*   el     = (int*)(ws + O_EL);
    float* src    = (float*)(ws + O_SRC);
    u16*   hbuf   = (u16*)(ws + O_H);
    u16*   txt    = (u16*)(ws + O_TXT);

    // dtype detect + canonicalize
    k_detect<<<1, 256, 0, stream>>>((const u16*)x, flagp);
    k_convert<<<(CTOT+255)/256, 256, 0, stream>>>(flagp,
        x, d_in[3], d_in[4], d_in[5], d_in[6], d_in[7], d_in[8], d_in[9],
        d_in[10], d_in[11], d_in[12], d_in[13], d_in[14], d_in[15], d_in[16], d_in[17],
        canon);

    const float* cx   = canon + CX;
    const float* cw1  = canon + CW1;
    const float* cb1  = canon + CB1;
    const float* cw2  = canon + CW2;
    const float* cb2  = canon + CB2;
    const float* cemb = canon + CEMB;
    const float* cwih = canon + CWIH;
    const float* cwhh = canon + CWHH;
    const float* cbih = canon + CBIH;
    const float* cbhh = canon + CBHH;
    const float* cl1w = canon + CL1W;
    const float* cl1b = canon + CL1B;
    const float* cltw = canon + CLTW;
    const float* cltb = canon + CLTB;
    const float* clfw = canon + CLFW;
    const float* clfb = canon + CLFB;

    // CSR build (once; reused by both GCN layers)
    hipMemsetAsync(deg, 0, (size_t)N_NODES*4, stream);
    k_hist <<<(N_EDGES+255)/256, 256, 0, stream>>>(ei, deg);
    k_scan1<<<NBLK, 256, 0, stream>>>(deg, rowptr, bsum);
    k_scan2<<<1, 512, 0, stream>>>(bsum);
    k_scan3<<<NBLK, 256, 0, stream>>>(deg, bsum, rowptr, cursor, dinv);
    k_fill <<<(N_EDGES+255)/256, 256, 0, stream>>>(ei, cursor, el);

    // weight packing + gi table (tiny)
    k_packb<<<(64*64+255)/256, 256, 0, stream>>>(cw2, w2p, 64, 64, 64, 1);
    k_packb<<<(64*192+255)/256, 256, 0, stream>>>(cwhh, whhp, 64, 192, 1, 64);
    k_packb<<<(128*64+255)/256, 256, 0, stream>>>(cl1w, l1p, 128, 64, 1, 128);
    k_packb<<<(128*64+255)/256, 256, 0, stream>>>(cltw, ltp, 128, 64, 1, 128);
    k_gitab<<<(64*192+255)/256, 256, 0, stream>>>(cemb, cwih, cbih, giT);

    // GCN layer 1
    k_t1s<<<N_NODES*64/256, 256, 0, stream>>>(cx, cw1, dinv, src);
    k_gather_ep<<<N_NODES*64/256, 256, 0, stream>>>(rowptr, el, src, dinv, cb1, hbuf);

    // GCN layer 2
    k_conv2<<<(N_NODES/16 + 3)/4, 256, 0, stream>>>(hbuf, w2p, dinv, src);
    k_gather_ep<<<N_NODES*64/256, 256, 0, stream>>>(rowptr, el, src, dinv, cb2, hbuf);

    // GRU over text
    k_gru<<<(N_NODES/16 + 3)/4, 256, 0, stream>>>(xt, whhp, giT, cbhh, txt);

    // edge-pair MLPs + final + log_softmax
    k_edge<<<2048, 256, 0, stream>>>(ei, hbuf, txt, l1p, ltp, cl1b, cltb, clfw, clfb,
                                     flagp, d_out);
}

// Round 5
// 542.002 us; speedup vs baseline: 1.6835x; 1.1223x over previous
//
#include <hip/hip_runtime.h>
#include <stdint.h>

#define N_NODES 100000
#define N_EDGES 1000000
#define NBLK 391   // ceil(N_NODES/256)

typedef unsigned short u16;
typedef unsigned int u32;
typedef __attribute__((ext_vector_type(8))) short bshort8;
typedef __attribute__((ext_vector_type(4))) float f32x4;

__device__ __forceinline__ float bf2f(u16 u){ union{float f; u32 i;} x; x.i=((u32)u)<<16; return x.f; }
__device__ __forceinline__ u16 f2bf(float f){ union{float f; u32 i;} x; x.f=f; u32 r = x.i + 0x7FFFu + ((x.i>>16)&1u); return (u16)(r>>16); }

__device__ __forceinline__ float fexp2(float x){
#if __has_builtin(__builtin_amdgcn_exp2f)
    return __builtin_amdgcn_exp2f(x);
#else
    return exp2f(x);
#endif
}
__device__ __forceinline__ float frcp(float x){
#if __has_builtin(__builtin_amdgcn_rcpf)
    return __builtin_amdgcn_rcpf(x);
#else
    return 1.0f/x;
#endif
}
#define LOG2E 1.442695041f

// ---------------- dtype detector (f32 vs bf16 device buffers) ----------------
__global__ void k_detect(const u16* __restrict__ x, int* flagp){
    __shared__ int cnt;
    if(threadIdx.x == 0) cnt = 0;
    __syncthreads();
    int c = 0;
    for(int i = threadIdx.x; i < 2048; i += 256){
        int e = (x[i] >> 7) & 0xFF;
        if(e >= 0x90) c++;
    }
    atomicAdd(&cnt, c);
    __syncthreads();
    if(threadIdx.x == 0) flagp[0] = (cnt > 64) ? 1 : 0;   // 1 = f32, 0 = bf16
}

// canonical f32 table offsets
#define CX    0
#define CW1   800000
#define CB1   800512
#define CW2   800576
#define CB2   804672
#define CEMB  804736
#define CWIH  808832
#define CWHH  821120
#define CBIH  833408
#define CBHH  833600
#define CL1W  833792
#define CL1B  841984
#define CLTW  842048
#define CLTB  850240
#define CLFW  850304
#define CLFB  850560
#define CTOT  850562

__device__ __forceinline__ float ldany(const void* p, int i, int fl){
    return fl ? ((const float*)p)[i] : bf2f(((const u16*)p)[i]);
}

__global__ void k_convert(const int* __restrict__ flagp,
                          const void* x, const void* w1, const void* b1, const void* w2,
                          const void* b2, const void* emb, const void* wih, const void* whh,
                          const void* bih, const void* bhh, const void* l1w, const void* l1b,
                          const void* ltw, const void* ltb, const void* lfw, const void* lfb,
                          float* __restrict__ canon){
    int i = blockIdx.x*256 + threadIdx.x;
    if(i >= CTOT) return;
    int fl = *flagp;
    const void* p; int off;
    if     (i < CW1 ){ p = x;   off = i;        }
    else if(i < CB1 ){ p = w1;  off = i - CW1;  }
    else if(i < CW2 ){ p = b1;  off = i - CB1;  }
    else if(i < CB2 ){ p = w2;  off = i - CW2;  }
    else if(i < CEMB){ p = b2;  off = i - CB2;  }
    else if(i < CWIH){ p = emb; off = i - CEMB; }
    else if(i < CWHH){ p = wih; off = i - CWIH; }
    else if(i < CBIH){ p = whh; off = i - CWHH; }
    else if(i < CBHH){ p = bih; off = i - CBIH; }
    else if(i < CL1W){ p = bhh; off = i - CBHH; }
    else if(i < CL1B){ p = l1w; off = i - CL1W; }
    else if(i < CLTW){ p = l1b; off = i - CL1B; }
    else if(i < CLTB){ p = ltw; off = i - CLTW; }
    else if(i < CLFW){ p = ltb; off = i - CLTB; }
    else if(i < CLFB){ p = lfw; off = i - CLFW; }
    else             { p = lfb; off = i - CLFB; }
    float v = ldany(p, off, fl);
    canon[i] = (v == v && fabsf(v) < 1e30f) ? v : 0.f;
}

// ---------------- CSR build: histogram -> scan -> fill ----------------
__global__ void k_hist(const int* __restrict__ ei, int* __restrict__ deg){
    int e = blockIdx.x*256 + threadIdx.x;
    if(e < N_EDGES) atomicAdd(&deg[ei[N_EDGES + e]], 1);
}
__global__ void k_scan1(const int* __restrict__ deg, int* __restrict__ rowptr,
                        int* __restrict__ bsum){
    __shared__ int sh[256];
    int tid = threadIdx.x;
    int i = blockIdx.x*256 + tid;
    int v = (i < N_NODES) ? deg[i] : 0;
    sh[tid] = v;
    __syncthreads();
    for(int off = 1; off < 256; off <<= 1){
        int t = (tid >= off) ? sh[tid - off] : 0;
        __syncthreads();
        sh[tid] += t;
        __syncthreads();
    }
    if(i < N_NODES) rowptr[i] = sh[tid] - v;     // exclusive within block
    if(tid == 255) bsum[blockIdx.x] = sh[255];
}
__global__ void k_scan2(int* __restrict__ bsum){
    __shared__ int sh[512];
    int tid = threadIdx.x;
    int v = (tid < NBLK) ? bsum[tid] : 0;
    sh[tid] = v;
    __syncthreads();
    for(int off = 1; off < 512; off <<= 1){
        int t = (tid >= off) ? sh[tid - off] : 0;
        __syncthreads();
        sh[tid] += t;
        __syncthreads();
    }
    if(tid < NBLK) bsum[tid] = sh[tid] - v;      // exclusive block offsets
}
__global__ void k_scan3(const int* __restrict__ deg, const int* __restrict__ bsum,
                        int* __restrict__ rowptr, int* __restrict__ cursor,
                        float* __restrict__ dinv){
    int i = blockIdx.x*256 + threadIdx.x;
    if(i < N_NODES){
        int r = rowptr[i] + bsum[i >> 8];
        rowptr[i] = r;
        cursor[i] = r;
        dinv[i] = rsqrtf((float)deg[i] + 1.0f);   // +1 self loop
    }
    if(i == 0) rowptr[N_NODES] = N_EDGES;
}
__global__ void k_fill(const int* __restrict__ ei, int* __restrict__ cursor,
                       int* __restrict__ el){
    int e = blockIdx.x*256 + threadIdx.x;
    if(e < N_EDGES){
        int s = ei[e], d = ei[N_EDGES + e];
        int pos = atomicAdd(&cursor[d], 1);
        el[pos] = s;
    }
}

// ---------------- conv1: src = (x @ W1) * dinv   (f32) ----------------
__global__ void k_t1s(const float* __restrict__ cx, const float* __restrict__ cw1,
                      const float* __restrict__ dinv, float* __restrict__ src){
    __shared__ float w[512];
    int t = threadIdx.x;
    w[t]       = cw1[t];
    w[t + 256] = cw1[t + 256];
    __syncthreads();
    int i = blockIdx.x*256 + t;      // grid exactly N*64/256
    int n = i >> 6, f = i & 63;
    const float* xr = cx + n*8;
    float acc = 0.f;
    #pragma unroll
    for(int k = 0; k < 8; k++) acc += xr[k] * w[k*64 + f];
    src[i] = acc * dinv[n];
}

// ---------------- fused gather + epilogue ----------------
__global__ __launch_bounds__(256)
void k_gather_ep(const int* __restrict__ rowptr, const int* __restrict__ el,
                 const float* __restrict__ src, const float* __restrict__ dinv,
                 const float* __restrict__ b, u16* __restrict__ h){
    int gid = blockIdx.x*256 + threadIdx.x;   // grid exactly N*64/256
    int node = gid >> 6, lane = gid & 63;
    int beg = rowptr[node], end = rowptr[node + 1];
    float acc = src[node*64 + lane];          // self loop
    int i = beg;
    for(; i + 4 <= end; i += 4){
        int s0 = el[i], s1 = el[i+1], s2 = el[i+2], s3 = el[i+3];
        float a0 = src[s0*64 + lane];
        float a1 = src[s1*64 + lane];
        float a2 = src[s2*64 + lane];
        float a3 = src[s3*64 + lane];
        acc += a0; acc += a1; acc += a2; acc += a3;
    }
    for(; i < end; i++) acc += src[el[i]*64 + lane];
    h[node*64 + lane] = f2bf(fmaxf(dinv[node]*acc + b[lane], 0.f));
}

// ---------------- pack B matrix (f32 canon -> bf16 MFMA fragment order) ----------------
__global__ void k_packb(const float* __restrict__ src, u16* __restrict__ dst,
                        int K, int N, int ldk, int ldn){
    int i = blockIdx.x*256 + threadIdx.x;
    if(i >= K*N) return;
    int k = i / N, n = i % N;
    int kt = k >> 5, kk = k & 31, q = kk >> 3, j = kk & 7;
    int nt = n >> 4, nn = n & 15;
    int KT = K >> 5;
    dst[(((nt*KT + kt)*64) + (q*16 + nn))*8 + j] = f2bf(src[k*ldk + n*ldn]);
}

// ---------------- gi table: gi[v][g] = b_ih[g] + sum_f w_ih[g][f]*embed[v][f]
//                  + b_hh[g] folded in for r,z groups (g<128) ----------------
__global__ void k_gitab(const float* __restrict__ emb, const float* __restrict__ wih,
                        const float* __restrict__ bih, const float* __restrict__ bhh,
                        float* __restrict__ giT){
    int i = blockIdx.x*256 + threadIdx.x;
    if(i >= 64*192) return;
    int v = i / 192, g = i % 192;
    float acc = bih[g] + ((g < 128) ? bhh[g] : 0.0f);
    const float* wr = wih + g*64;
    const float* er = emb + v*64;
    for(int f = 0; f < 64; f++) acc += wr[f] * er[f];
    giT[i] = acc;
}

// ---------------- conv2 GEMM: src = (h1 @ W2) * dinv ----------------
__global__ __launch_bounds__(256, 4)
void k_conv2(const u16* __restrict__ h, const u16* __restrict__ w2p,
             const float* __restrict__ dinv, float* __restrict__ src){
    int wv = threadIdx.x >> 6, lane = threadIdx.x & 63;
    int g = blockIdx.x*4 + wv;
    if(g >= N_NODES/16) return;
    int q = lane >> 4, m = lane & 15, col = m;
    bshort8 a0 = *(const bshort8*)(h + (g*16 + m)*64 + q*8);
    bshort8 a1 = *(const bshort8*)(h + (g*16 + m)*64 + 32 + q*8);
    f32x4 acc[4];
    #pragma unroll
    for(int nt = 0; nt < 4; nt++){
        f32x4 c = {0.f,0.f,0.f,0.f};
        c = __builtin_amdgcn_mfma_f32_16x16x32_bf16(a0, *(const bshort8*)(w2p + ((nt*2+0)*64 + lane)*8), c, 0,0,0);
        c = __builtin_amdgcn_mfma_f32_16x16x32_bf16(a1, *(const bshort8*)(w2p + ((nt*2+1)*64 + lane)*8), c, 0,0,0);
        acc[nt] = c;
    }
    #pragma unroll
    for(int nt = 0; nt < 4; nt++)
        #pragma unroll
        for(int r = 0; r < 4; r++){
            int node = g*16 + q*4 + r;
            src[node*64 + nt*16 + col] = acc[nt][r] * dinv[node];
        }
}

// ---------------- GRU: wave per 16 nodes; Whh in LDS; native rcp/exp2; no step barriers ----------------
__global__ __launch_bounds__(256, 3)
void k_gru(const int* __restrict__ xt, const u16* __restrict__ whhp,
           const float* __restrict__ giT, const float* __restrict__ bhh,
           u16* __restrict__ txt){
    __shared__ __align__(16) u16 wsh[12288];         // 24 KB: 24 packed Whh frags
    __shared__ __align__(16) float hsh[4][16][68];   // f32 h tile per wave (+4 pad)
    int tid = threadIdx.x;
    {   // cooperative stage Whh fragments -> LDS
        const uint4* s = (const uint4*)whhp;
        uint4* d = (uint4*)wsh;
        #pragma unroll
        for(int i = 0; i < 6; i++) d[tid + 256*i] = s[tid + 256*i];
    }
    __syncthreads();

    int wv = tid >> 6, lane = tid & 63;
    int q = lane >> 4, m = lane & 15, col = m;
    int g = blockIdx.x*4 + wv;
    bool active = g < (N_NODES/16);
    int nb = active ? g*16 : 0;

    float bhhn[4];
    #pragma unroll
    for(int t = 0; t < 4; t++) bhhn[t] = bhh[128 + t*16 + col];

    const bshort8* wl = (const bshort8*)wsh;   // frag i at wl[i*64 + lane]
    float* hp = &hsh[wv][m][0];                // A-read base (row m)

    float hc[4][4];
    #pragma unroll
    for(int t = 0; t < 4; t++)
        #pragma unroll
        for(int r = 0; r < 4; r++) hc[t][r] = 0.f;

    for(int s = 0; s < 10; s++){
        // write h (f32) to per-wave LDS tile; in-wave DS ordering makes this safe barrier-free
        #pragma unroll
        for(int t = 0; t < 4; t++)
            #pragma unroll
            for(int r = 0; r < 4; r++)
                hsh[wv][q*4 + r][t*16 + col] = hc[t][r];

        // read back row m as A-fragments, pack f32->bf16
        float4 x0 = *(float4*)(hp + q*8);
        float4 x1 = *(float4*)(hp + q*8 + 4);
        float4 x2 = *(float4*)(hp + 32 + q*8);
        float4 x3 = *(float4*)(hp + 32 + q*8 + 4);
        u32 aw[8];
        aw[0] = (u32)f2bf(x0.x) | ((u32)f2bf(x0.y) << 16);
        aw[1] = (u32)f2bf(x0.z) | ((u32)f2bf(x0.w) << 16);
        aw[2] = (u32)f2bf(x1.x) | ((u32)f2bf(x1.y) << 16);
        aw[3] = (u32)f2bf(x1.z) | ((u32)f2bf(x1.w) << 16);
        aw[4] = (u32)f2bf(x2.x) | ((u32)f2bf(x2.y) << 16);
        aw[5] = (u32)f2bf(x2.z) | ((u32)f2bf(x2.w) << 16);
        aw[6] = (u32)f2bf(x3.x) | ((u32)f2bf(x3.y) << 16);
        aw[7] = (u32)f2bf(x3.z) | ((u32)f2bf(x3.w) << 16);
        bshort8 a0 = *(bshort8*)&aw[0];
        bshort8 a1 = *(bshort8*)&aw[4];

        int tok[4];
        #pragma unroll
        for(int r = 0; r < 4; r++) tok[r] = xt[(nb + q*4 + r)*10 + s] & 63;

        f32x4 acc[12];
        #pragma unroll
        for(int nt = 0; nt < 12; nt++){
            f32x4 c = {0.f,0.f,0.f,0.f};
            c = __builtin_amdgcn_mfma_f32_16x16x32_bf16(a0, wl[(nt*2+0)*64 + lane], c, 0,0,0);
            c = __builtin_amdgcn_mfma_f32_16x16x32_bf16(a1, wl[(nt*2+1)*64 + lane], c, 0,0,0);
            acc[nt] = c;
        }

        #pragma unroll
        for(int r = 0; r < 4; r++){
            const float* gp = giT + tok[r]*192 + col;
            #pragma unroll
            for(int t = 0; t < 4; t++){
                float gir = gp[t*16], giz = gp[64 + t*16], gin = gp[128 + t*16];
                float rr = frcp(1.0f + fexp2(-LOG2E*(gir + acc[t][r])));
                float zz = frcp(1.0f + fexp2(-LOG2E*(giz + acc[4+t][r])));
                float narg = gin + rr*(acc[8+t][r] + bhhn[t]);
                float e2 = fexp2(2.0f*LOG2E*narg);
                float nn = 1.0f - 2.0f*frcp(e2 + 1.0f);
                hc[t][r] = nn + zz*(hc[t][r] - nn);
            }
        }
        asm volatile("" ::: "memory");   // keep DS reads inside the loop (stop invariant hoist)
    }
    if(active){
        #pragma unroll
        for(int t = 0; t < 4; t++)
            #pragma unroll
            for(int r = 0; r < 4; r++)
                txt[(nb + q*4 + r)*64 + t*16 + col] = f2bf(hc[t][r]);
    }
}

// ---------------- edge MLP + final + log_softmax ----------------
__global__ __launch_bounds__(256, 2)
void k_edge(const int* __restrict__ ei, const u16* __restrict__ h2, const u16* __restrict__ txt,
            const u16* __restrict__ l1p, const u16* __restrict__ ltp,
            const float* __restrict__ b1, const float* __restrict__ bt,
            const float* __restrict__ wfin, const float* __restrict__ bfin,
            const int* __restrict__ flagp, void* __restrict__ out){
    int lane = threadIdx.x & 63;
    int q = lane >> 4, m = lane & 15, col = m;
    int wgid = (blockIdx.x*256 + threadIdx.x) >> 6;
    int nw = (gridDim.x*256) >> 6;
    int fl = *flagp;

    bshort8 wa[16], wb[16];
    #pragma unroll
    for(int i = 0; i < 16; i++){
        wa[i] = *(const bshort8*)(l1p + (i*64 + lane)*8);
        wb[i] = *(const bshort8*)(ltp + (i*64 + lane)*8);
    }
    float b1c[4], btc[4], wfp[2][4], wft[2][4];
    #pragma unroll
    for(int t = 0; t < 4; t++){
        b1c[t] = b1[t*16 + col];
        btc[t] = bt[t*16 + col];
        wfp[0][t] = wfin[t*16 + col];        wfp[1][t] = wfin[128 + t*16 + col];
        wft[0][t] = wfin[64 + t*16 + col];   wft[1][t] = wfin[128 + 64 + t*16 + col];
    }
    float bf0 = bfin[0], bf1 = bfin[1];

    for(int g = wgid; g < N_EDGES/16; g += nw){
        int e = g*16 + m;
        int s = ei[e], d = ei[N_EDGES + e];
        bshort8 a0 = *(const bshort8*)(h2 + s*64 + q*8);
        bshort8 a1 = *(const bshort8*)(h2 + s*64 + 32 + q*8);
        bshort8 a2 = *(const bshort8*)(h2 + d*64 + q*8);
        bshort8 a3 = *(const bshort8*)(h2 + d*64 + 32 + q*8);
        f32x4 p[4];
        #pragma unroll
        for(int nt = 0; nt < 4; nt++){
            f32x4 c = {0.f,0.f,0.f,0.f};
            c = __builtin_amdgcn_mfma_f32_16x16x32_bf16(a0, wa[nt*4+0], c, 0,0,0);
            c = __builtin_amdgcn_mfma_f32_16x16x32_bf16(a1, wa[nt*4+1], c, 0,0,0);
            c = __builtin_amdgcn_mfma_f32_16x16x32_bf16(a2, wa[nt*4+2], c, 0,0,0);
            c = __builtin_amdgcn_mfma_f32_16x16x32_bf16(a3, wa[nt*4+3], c, 0,0,0);
            p[nt] = c;
        }
        bshort8 c0 = *(const bshort8*)(txt + s*64 + q*8);
        bshort8 c1 = *(const bshort8*)(txt + s*64 + 32 + q*8);
        bshort8 c2 = *(const bshort8*)(txt + d*64 + q*8);
        bshort8 c3 = *(const bshort8*)(txt + d*64 + 32 + q*8);
        f32x4 pt[4];
        #pragma unroll
        for(int nt = 0; nt < 4; nt++){
            f32x4 c = {0.f,0.f,0.f,0.f};
            c = __builtin_amdgcn_mfma_f32_16x16x32_bf16(c0, wb[nt*4+0], c, 0,0,0);
            c = __builtin_amdgcn_mfma_f32_16x16x32_bf16(c1, wb[nt*4+1], c, 0,0,0);
            c = __builtin_amdgcn_mfma_f32_16x16x32_bf16(c2, wb[nt*4+2], c, 0,0,0);
            c = __builtin_amdgcn_mfma_f32_16x16x32_bf16(c3, wb[nt*4+3], c, 0,0,0);
            pt[nt] = c;
        }
        float l0[4], l1[4];
        #pragma unroll
        for(int r = 0; r < 4; r++){
            float s0 = 0.f, s1 = 0.f;
            #pragma unroll
            for(int t = 0; t < 4; t++){
                float xp = fmaxf(p[t][r]  + b1c[t], 0.f);
                float xq = fmaxf(pt[t][r] + btc[t], 0.f);
                s0 += xp*wfp[0][t] + xq*wft[0][t];
                s1 += xp*wfp[1][t] + xq*wft[1][t];
            }
            l0[r] = s0; l1[r] = s1;
        }
        #pragma unroll
        for(int r = 0; r < 4; r++)
            #pragma unroll
            for(int msk = 1; msk < 16; msk <<= 1){
                l0[r] += __shfl_xor(l0[r], msk, 64);
                l1[r] += __shfl_xor(l1[r], msk, 64);
            }
        if(m == 0){
            #pragma unroll
            for(int r = 0; r < 4; r++){
                float a = l0[r] + bf0, b = l1[r] + bf1;
                float mx = fmaxf(a, b);
                float lse = mx + __logf(__expf(a - mx) + __expf(b - mx));
                int oi = g*16 + q*4 + r;
                if(fl){
                    float2 v; v.x = a - lse; v.y = b - lse;
                    ((float2*)out)[oi] = v;
                }else{
                    u32 pack = (u32)f2bf(a - lse) | ((u32)f2bf(b - lse) << 16);
                    ((u32*)out)[oi] = pack;
                }
            }
        }
    }
}

// ---------------- workspace layout (~60.3 MB) ----------------
static const size_t O_FLAG   = 0;
static const size_t O_CANON  = 4096;
static const size_t O_GIT    = 3407872;
static const size_t O_W2P    = 3457024;
static const size_t O_WHHP   = 3465216;
static const size_t O_L1P    = 3489792;
static const size_t O_LTP    = 3506176;
static const size_t O_DINV   = 3522560;
static const size_t O_DEG    = 3922560;
static const size_t O_ROWPTR = 4322560;
static const size_t O_CURSOR = 4722688;
static const size_t O_BSUM   = 5122688;
static const size_t O_EL     = 5124736;
static const size_t O_SRC    = 9124864;
static const size_t O_H      = 34724864;
static const size_t O_TXT    = 47524864;
// end = 60,324,864

extern "C" void kernel_launch(void* const* d_in, const int* in_sizes, int n_in,
                              void* d_out, int out_size, void* d_ws, size_t ws_size,
                              hipStream_t stream){
    const void* x    = d_in[0];
    const int*  ei   = (const int*)d_in[1];
    const int*  xt   = (const int*)d_in[2];

    char* ws = (char*)d_ws;
    int*   flagp  = (int*)(ws + O_FLAG);
    float* canon  = (float*)(ws + O_CANON);
    float* giT    = (float*)(ws + O_GIT);
    u16*   w2p    = (u16*)(ws + O_W2P);
    u16*   whhp   = (u16*)(ws + O_WHHP);
    u16*   l1p    = (u16*)(ws + O_L1P);
    u16*   ltp    = (u16*)(ws + O_LTP);
    float* dinv   = (float*)(ws + O_DINV);
    int*   deg    = (int*)(ws + O_DEG);
    int*   rowptr = (int*)(ws + O_ROWPTR);
    int*   cursor = (int*)(ws + O_CURSOR);
    int*   bsum   = (int*)(ws + O_BSUM);
    int*   el     = (int*)(ws + O_EL);
    float* src    = (float*)(ws + O_SRC);
    u16*   hbuf   = (u16*)(ws + O_H);
    u16*   txt    = (u16*)(ws + O_TXT);

    // dtype detect + canonicalize
    k_detect<<<1, 256, 0, stream>>>((const u16*)x, flagp);
    k_convert<<<(CTOT+255)/256, 256, 0, stream>>>(flagp,
        x, d_in[3], d_in[4], d_in[5], d_in[6], d_in[7], d_in[8], d_in[9],
        d_in[10], d_in[11], d_in[12], d_in[13], d_in[14], d_in[15], d_in[16], d_in[17],
        canon);

    const float* cx   = canon + CX;
    const float* cw1  = canon + CW1;
    const float* cb1  = canon + CB1;
    const float* cw2  = canon + CW2;
    const float* cb2  = canon + CB2;
    const float* cemb = canon + CEMB;
    const float* cwih = canon + CWIH;
    const float* cwhh = canon + CWHH;
    const float* cbih = canon + CBIH;
    const float* cbhh = canon + CBHH;
    const float* cl1w = canon + CL1W;
    const float* cl1b = canon + CL1B;
    const float* cltw = canon + CLTW;
    const float* cltb = canon + CLTB;
    const float* clfw = canon + CLFW;
    const float* clfb = canon + CLFB;

    // CSR build (once; reused by both GCN layers)
    hipMemsetAsync(deg, 0, (size_t)N_NODES*4, stream);
    k_hist <<<(N_EDGES+255)/256, 256, 0, stream>>>(ei, deg);
    k_scan1<<<NBLK, 256, 0, stream>>>(deg, rowptr, bsum);
    k_scan2<<<1, 512, 0, stream>>>(bsum);
    k_scan3<<<NBLK, 256, 0, stream>>>(deg, bsum, rowptr, cursor, dinv);
    k_fill <<<(N_EDGES+255)/256, 256, 0, stream>>>(ei, cursor, el);

    // weight packing + gi table (tiny)
    k_packb<<<(64*64+255)/256, 256, 0, stream>>>(cw2, w2p, 64, 64, 64, 1);
    k_packb<<<(64*192+255)/256, 256, 0, stream>>>(cwhh, whhp, 64, 192, 1, 64);
    k_packb<<<(128*64+255)/256, 256, 0, stream>>>(cl1w, l1p, 128, 64, 1, 128);
    k_packb<<<(128*64+255)/256, 256, 0, stream>>>(cltw, ltp, 128, 64, 1, 128);
    k_gitab<<<(64*192+255)/256, 256, 0, stream>>>(cemb, cwih, cbih, cbhh, giT);

    // GCN layer 1
    k_t1s<<<N_NODES*64/256, 256, 0, stream>>>(cx, cw1, dinv, src);
    k_gather_ep<<<N_NODES*64/256, 256, 0, stream>>>(rowptr, el, src, dinv, cb1, hbuf);

    // GCN layer 2
    k_conv2<<<(N_NODES/16 + 3)/4, 256, 0, stream>>>(hbuf, w2p, dinv, src);
    k_gather_ep<<<N_NODES*64/256, 256, 0, stream>>>(rowptr, el, src, dinv, cb2, hbuf);

    // GRU over text
    k_gru<<<(N_NODES/16 + 3)/4, 256, 0, stream>>>(xt, whhp, giT, cbhh, txt);

    // edge-pair MLPs + final + log_softmax
    k_edge<<<2048, 256, 0, stream>>>(ei, hbuf, txt, l1p, ltp, cl1b, cltb, clfw, clfb,
                                     flagp, d_out);
}

// Round 6
// 529.927 us; speedup vs baseline: 1.7219x; 1.0228x over previous
//
#include <hip/hip_runtime.h>
#include <stdint.h>

#define N_NODES 100000
#define N_EDGES 1000000
#define NBLK 391   // ceil(N_NODES/256)

typedef unsigned short u16;
typedef unsigned int u32;
typedef __attribute__((ext_vector_type(8))) short bshort8;
typedef __attribute__((ext_vector_type(4))) float f32x4;

__device__ __forceinline__ float bf2f(u16 u){ union{float f; u32 i;} x; x.i=((u32)u)<<16; return x.f; }
__device__ __forceinline__ u16 f2bf(float f){ union{float f; u32 i;} x; x.f=f; u32 r = x.i + 0x7FFFu + ((x.i>>16)&1u); return (u16)(r>>16); }

__device__ __forceinline__ float fexp2(float x){
#if __has_builtin(__builtin_amdgcn_exp2f)
    return __builtin_amdgcn_exp2f(x);
#else
    return exp2f(x);
#endif
}
__device__ __forceinline__ float frcp(float x){
#if __has_builtin(__builtin_amdgcn_rcpf)
    return __builtin_amdgcn_rcpf(x);
#else
    return 1.0f/x;
#endif
}
#define LOG2E 1.442695041f

// ---------------- dtype detector (f32 vs bf16 device buffers) ----------------
__global__ void k_detect(const u16* __restrict__ x, int* flagp){
    __shared__ int cnt;
    if(threadIdx.x == 0) cnt = 0;
    __syncthreads();
    int c = 0;
    for(int i = threadIdx.x; i < 2048; i += 256){
        int e = (x[i] >> 7) & 0xFF;
        if(e >= 0x90) c++;
    }
    atomicAdd(&cnt, c);
    __syncthreads();
    if(threadIdx.x == 0) flagp[0] = (cnt > 64) ? 1 : 0;   // 1 = f32, 0 = bf16
}

// canonical f32 table offsets
#define CX    0
#define CW1   800000
#define CB1   800512
#define CW2   800576
#define CB2   804672
#define CEMB  804736
#define CWIH  808832
#define CWHH  821120
#define CBIH  833408
#define CBHH  833600
#define CL1W  833792
#define CL1B  841984
#define CLTW  842048
#define CLTB  850240
#define CLFW  850304
#define CLFB  850560
#define CTOT  850562

__device__ __forceinline__ float ldany(const void* p, int i, int fl){
    return fl ? ((const float*)p)[i] : bf2f(((const u16*)p)[i]);
}

__global__ void k_convert(const int* __restrict__ flagp,
                          const void* x, const void* w1, const void* b1, const void* w2,
                          const void* b2, const void* emb, const void* wih, const void* whh,
                          const void* bih, const void* bhh, const void* l1w, const void* l1b,
                          const void* ltw, const void* ltb, const void* lfw, const void* lfb,
                          float* __restrict__ canon){
    int i = blockIdx.x*256 + threadIdx.x;
    if(i >= CTOT) return;
    int fl = *flagp;
    const void* p; int off;
    if     (i < CW1 ){ p = x;   off = i;        }
    else if(i < CB1 ){ p = w1;  off = i - CW1;  }
    else if(i < CW2 ){ p = b1;  off = i - CB1;  }
    else if(i < CB2 ){ p = w2;  off = i - CW2;  }
    else if(i < CEMB){ p = b2;  off = i - CB2;  }
    else if(i < CWIH){ p = emb; off = i - CEMB; }
    else if(i < CWHH){ p = wih; off = i - CWIH; }
    else if(i < CBIH){ p = whh; off = i - CWHH; }
    else if(i < CBHH){ p = bih; off = i - CBIH; }
    else if(i < CL1W){ p = bhh; off = i - CBHH; }
    else if(i < CL1B){ p = l1w; off = i - CL1W; }
    else if(i < CLTW){ p = l1b; off = i - CL1B; }
    else if(i < CLTB){ p = ltw; off = i - CLTW; }
    else if(i < CLFW){ p = ltb; off = i - CLTB; }
    else if(i < CLFB){ p = lfw; off = i - CLFW; }
    else             { p = lfb; off = i - CLFB; }
    float v = ldany(p, off, fl);
    canon[i] = (v == v && fabsf(v) < 1e30f) ? v : 0.f;
}

// ---------------- CSR build: histogram -> scan -> fill (el, dl, eid) ----------------
__global__ void k_hist(const int* __restrict__ ei, int* __restrict__ deg){
    int e = blockIdx.x*256 + threadIdx.x;
    if(e < N_EDGES) atomicAdd(&deg[ei[N_EDGES + e]], 1);
}
__global__ void k_scan1(const int* __restrict__ deg, int* __restrict__ rowptr,
                        int* __restrict__ bsum){
    __shared__ int sh[256];
    int tid = threadIdx.x;
    int i = blockIdx.x*256 + tid;
    int v = (i < N_NODES) ? deg[i] : 0;
    sh[tid] = v;
    __syncthreads();
    for(int off = 1; off < 256; off <<= 1){
        int t = (tid >= off) ? sh[tid - off] : 0;
        __syncthreads();
        sh[tid] += t;
        __syncthreads();
    }
    if(i < N_NODES) rowptr[i] = sh[tid] - v;
    if(tid == 255) bsum[blockIdx.x] = sh[255];
}
__global__ void k_scan2(int* __restrict__ bsum){
    __shared__ int sh[512];
    int tid = threadIdx.x;
    int v = (tid < NBLK) ? bsum[tid] : 0;
    sh[tid] = v;
    __syncthreads();
    for(int off = 1; off < 512; off <<= 1){
        int t = (tid >= off) ? sh[tid - off] : 0;
        __syncthreads();
        sh[tid] += t;
        __syncthreads();
    }
    if(tid < NBLK) bsum[tid] = sh[tid] - v;
}
__global__ void k_scan3(const int* __restrict__ deg, const int* __restrict__ bsum,
                        int* __restrict__ rowptr, int* __restrict__ cursor,
                        float* __restrict__ dinv){
    int i = blockIdx.x*256 + threadIdx.x;
    if(i < N_NODES){
        int r = rowptr[i] + bsum[i >> 8];
        rowptr[i] = r;
        cursor[i] = r;
        dinv[i] = rsqrtf((float)deg[i] + 1.0f);   // +1 self loop
    }
    if(i == 0) rowptr[N_NODES] = N_EDGES;
}
__global__ void k_fill(const int* __restrict__ ei, int* __restrict__ cursor,
                       int* __restrict__ el, int* __restrict__ dl, int* __restrict__ eid){
    int e = blockIdx.x*256 + threadIdx.x;
    if(e < N_EDGES){
        int s = ei[e], d = ei[N_EDGES + e];
        int pos = atomicAdd(&cursor[d], 1);
        el[pos] = s;
        dl[pos] = d;
        eid[pos] = e;
    }
}

// ---------------- conv1: src = bf16((x @ W1) * dinv) ----------------
__global__ void k_t1s(const float* __restrict__ cx, const float* __restrict__ cw1,
                      const float* __restrict__ dinv, u16* __restrict__ src){
    __shared__ float w[512];
    int t = threadIdx.x;
    w[t]       = cw1[t];
    w[t + 256] = cw1[t + 256];
    __syncthreads();
    int i = blockIdx.x*256 + t;      // grid exactly N*64/256
    int n = i >> 6, f = i & 63;
    const float* xr = cx + n*8;
    float acc = 0.f;
    #pragma unroll
    for(int k = 0; k < 8; k++) acc += xr[k] * w[k*64 + f];
    src[i] = f2bf(acc * dinv[n]);
}

// ---------------- fused gather + epilogue (bf16 src rows, strided bf16 out) ----------------
__global__ __launch_bounds__(256)
void k_gather_ep(const int* __restrict__ rowptr, const int* __restrict__ el,
                 const u16* __restrict__ src, const float* __restrict__ dinv,
                 const float* __restrict__ b, u16* __restrict__ h, int ostride){
    int gid = blockIdx.x*256 + threadIdx.x;   // grid exactly N*64/256
    int node = gid >> 6, lane = gid & 63;
    int beg = rowptr[node], end = rowptr[node + 1];
    float acc = bf2f(src[node*64 + lane]);    // self loop (pre-scaled by dinv[src])
    int i = beg;
    for(; i + 4 <= end; i += 4){
        int s0 = el[i], s1 = el[i+1], s2 = el[i+2], s3 = el[i+3];
        float a0 = bf2f(src[s0*64 + lane]);
        float a1 = bf2f(src[s1*64 + lane]);
        float a2 = bf2f(src[s2*64 + lane]);
        float a3 = bf2f(src[s3*64 + lane]);
        acc += a0; acc += a1; acc += a2; acc += a3;
    }
    for(; i < end; i++) acc += bf2f(src[el[i]*64 + lane]);
    h[node*ostride + lane] = f2bf(fmaxf(dinv[node]*acc + b[lane], 0.f));
}

// ---------------- pack B matrix (f32 canon -> bf16 MFMA fragment order) ----------------
__global__ void k_packb(const float* __restrict__ src, u16* __restrict__ dst,
                        int K, int N, int ldk, int ldn){
    int i = blockIdx.x*256 + threadIdx.x;
    if(i >= K*N) return;
    int k = i / N, n = i % N;
    int kt = k >> 5, kk = k & 31, q = kk >> 3, j = kk & 7;
    int nt = n >> 4, nn = n & 15;
    int KT = K >> 5;
    dst[(((nt*KT + kt)*64) + (q*16 + nn))*8 + j] = f2bf(src[k*ldk + n*ldn]);
}

// ---------------- gi table (b_hh folded for r,z) ----------------
__global__ void k_gitab(const float* __restrict__ emb, const float* __restrict__ wih,
                        const float* __restrict__ bih, const float* __restrict__ bhh,
                        float* __restrict__ giT){
    int i = blockIdx.x*256 + threadIdx.x;
    if(i >= 64*192) return;
    int v = i / 192, g = i % 192;
    float acc = bih[g] + ((g < 128) ? bhh[g] : 0.0f);
    const float* wr = wih + g*64;
    const float* er = emb + v*64;
    for(int f = 0; f < 64; f++) acc += wr[f] * er[f];
    giT[i] = acc;
}

// ---------------- conv2 GEMM: src = bf16((h1 @ W2) * dinv) ----------------
__global__ __launch_bounds__(256, 4)
void k_conv2(const u16* __restrict__ h, const u16* __restrict__ w2p,
             const float* __restrict__ dinv, u16* __restrict__ src){
    int wv = threadIdx.x >> 6, lane = threadIdx.x & 63;
    int g = blockIdx.x*4 + wv;
    if(g >= N_NODES/16) return;
    int q = lane >> 4, m = lane & 15, col = m;
    bshort8 a0 = *(const bshort8*)(h + (g*16 + m)*64 + q*8);
    bshort8 a1 = *(const bshort8*)(h + (g*16 + m)*64 + 32 + q*8);
    f32x4 acc[4];
    #pragma unroll
    for(int nt = 0; nt < 4; nt++){
        f32x4 c = {0.f,0.f,0.f,0.f};
        c = __builtin_amdgcn_mfma_f32_16x16x32_bf16(a0, *(const bshort8*)(w2p + ((nt*2+0)*64 + lane)*8), c, 0,0,0);
        c = __builtin_amdgcn_mfma_f32_16x16x32_bf16(a1, *(const bshort8*)(w2p + ((nt*2+1)*64 + lane)*8), c, 0,0,0);
        acc[nt] = c;
    }
    #pragma unroll
    for(int nt = 0; nt < 4; nt++)
        #pragma unroll
        for(int r = 0; r < 4; r++){
            int node = g*16 + q*4 + r;
            src[node*64 + nt*16 + col] = f2bf(acc[nt][r] * dinv[node]);
        }
}

// ---------------- GRU: wave per 16 nodes; Whh in LDS; strided output into nodef ----------------
__global__ __launch_bounds__(256, 3)
void k_gru(const int* __restrict__ xt, const u16* __restrict__ whhp,
           const float* __restrict__ giT, const float* __restrict__ bhh,
           u16* __restrict__ txt){   // txt = nodef + 64, stride 128
    __shared__ __align__(16) u16 wsh[12288];
    __shared__ __align__(16) float hsh[4][16][68];
    int tid = threadIdx.x;
    {
        const uint4* s = (const uint4*)whhp;
        uint4* d = (uint4*)wsh;
        #pragma unroll
        for(int i = 0; i < 6; i++) d[tid + 256*i] = s[tid + 256*i];
    }
    __syncthreads();

    int wv = tid >> 6, lane = tid & 63;
    int q = lane >> 4, m = lane & 15, col = m;
    int g = blockIdx.x*4 + wv;
    bool active = g < (N_NODES/16);
    int nb = active ? g*16 : 0;

    float bhhn[4];
    #pragma unroll
    for(int t = 0; t < 4; t++) bhhn[t] = bhh[128 + t*16 + col];

    const bshort8* wl = (const bshort8*)wsh;
    float* hp = &hsh[wv][m][0];

    float hc[4][4];
    #pragma unroll
    for(int t = 0; t < 4; t++)
        #pragma unroll
        for(int r = 0; r < 4; r++) hc[t][r] = 0.f;

    for(int s = 0; s < 10; s++){
        #pragma unroll
        for(int t = 0; t < 4; t++)
            #pragma unroll
            for(int r = 0; r < 4; r++)
                hsh[wv][q*4 + r][t*16 + col] = hc[t][r];

        float4 x0 = *(float4*)(hp + q*8);
        float4 x1 = *(float4*)(hp + q*8 + 4);
        float4 x2 = *(float4*)(hp + 32 + q*8);
        float4 x3 = *(float4*)(hp + 32 + q*8 + 4);
        u32 aw[8];
        aw[0] = (u32)f2bf(x0.x) | ((u32)f2bf(x0.y) << 16);
        aw[1] = (u32)f2bf(x0.z) | ((u32)f2bf(x0.w) << 16);
        aw[2] = (u32)f2bf(x1.x) | ((u32)f2bf(x1.y) << 16);
        aw[3] = (u32)f2bf(x1.z) | ((u32)f2bf(x1.w) << 16);
        aw[4] = (u32)f2bf(x2.x) | ((u32)f2bf(x2.y) << 16);
        aw[5] = (u32)f2bf(x2.z) | ((u32)f2bf(x2.w) << 16);
        aw[6] = (u32)f2bf(x3.x) | ((u32)f2bf(x3.y) << 16);
        aw[7] = (u32)f2bf(x3.z) | ((u32)f2bf(x3.w) << 16);
        bshort8 a0 = *(bshort8*)&aw[0];
        bshort8 a1 = *(bshort8*)&aw[4];

        int tok[4];
        #pragma unroll
        for(int r = 0; r < 4; r++) tok[r] = xt[(nb + q*4 + r)*10 + s] & 63;

        f32x4 acc[12];
        #pragma unroll
        for(int nt = 0; nt < 12; nt++){
            f32x4 c = {0.f,0.f,0.f,0.f};
            c = __builtin_amdgcn_mfma_f32_16x16x32_bf16(a0, wl[(nt*2+0)*64 + lane], c, 0,0,0);
            c = __builtin_amdgcn_mfma_f32_16x16x32_bf16(a1, wl[(nt*2+1)*64 + lane], c, 0,0,0);
            acc[nt] = c;
        }

        #pragma unroll
        for(int r = 0; r < 4; r++){
            const float* gp = giT + tok[r]*192 + col;
            #pragma unroll
            for(int t = 0; t < 4; t++){
                float gir = gp[t*16], giz = gp[64 + t*16], gin = gp[128 + t*16];
                float rr = frcp(1.0f + fexp2(-LOG2E*(gir + acc[t][r])));
                float zz = frcp(1.0f + fexp2(-LOG2E*(giz + acc[4+t][r])));
                float narg = gin + rr*(acc[8+t][r] + bhhn[t]);
                float e2 = fexp2(2.0f*LOG2E*narg);
                float nn = 1.0f - 2.0f*frcp(e2 + 1.0f);
                hc[t][r] = nn + zz*(hc[t][r] - nn);
            }
        }
        asm volatile("" ::: "memory");
    }
    if(active){
        #pragma unroll
        for(int t = 0; t < 4; t++)
            #pragma unroll
            for(int r = 0; r < 4; r++)
                txt[(size_t)(nb + q*4 + r)*128 + t*16 + col] = f2bf(hc[t][r]);
    }
}

// ---------------- edge MLP + final + log_softmax: CSR-ordered, wave per 16 edges ----------------
__global__ __launch_bounds__(256, 2)
void k_edge(const int* __restrict__ el, const int* __restrict__ dl, const int* __restrict__ eid,
            const u16* __restrict__ nodef,   // [N][128]: h2 at +0, txt at +64
            const u16* __restrict__ l1p, const u16* __restrict__ ltp,
            const float* __restrict__ b1, const float* __restrict__ bt,
            const float* __restrict__ wfin, const float* __restrict__ bfin,
            const int* __restrict__ flagp, void* __restrict__ out){
    int lane = threadIdx.x & 63;
    int q = lane >> 4, m = lane & 15, col = m;
    int wgid = (blockIdx.x*256 + threadIdx.x) >> 6;
    int nw = (gridDim.x*256) >> 6;
    int fl = *flagp;

    bshort8 wa[16], wb[16];
    #pragma unroll
    for(int i = 0; i < 16; i++){
        wa[i] = *(const bshort8*)(l1p + (i*64 + lane)*8);
        wb[i] = *(const bshort8*)(ltp + (i*64 + lane)*8);
    }
    float b1c[4], btc[4], wfp[2][4], wft[2][4];
    #pragma unroll
    for(int t = 0; t < 4; t++){
        b1c[t] = b1[t*16 + col];
        btc[t] = bt[t*16 + col];
        wfp[0][t] = wfin[t*16 + col];        wfp[1][t] = wfin[128 + t*16 + col];
        wft[0][t] = wfin[64 + t*16 + col];   wft[1][t] = wfin[128 + 64 + t*16 + col];
    }
    float bf0 = bfin[0], bf1 = bfin[1];

    for(int g = wgid; g < N_EDGES/16; g += nw){
        int pos = g*16 + m;
        int s = el[pos], d = dl[pos];
        const u16* sp = nodef + (size_t)s*128;
        const u16* dp = nodef + (size_t)d*128;
        bshort8 a0 = *(const bshort8*)(sp + q*8);
        bshort8 a1 = *(const bshort8*)(sp + 32 + q*8);
        bshort8 a2 = *(const bshort8*)(dp + q*8);
        bshort8 a3 = *(const bshort8*)(dp + 32 + q*8);
        bshort8 c0 = *(const bshort8*)(sp + 64 + q*8);
        bshort8 c1 = *(const bshort8*)(sp + 96 + q*8);
        bshort8 c2 = *(const bshort8*)(dp + 64 + q*8);
        bshort8 c3 = *(const bshort8*)(dp + 96 + q*8);
        f32x4 p[4];
        #pragma unroll
        for(int nt = 0; nt < 4; nt++){
            f32x4 c = {0.f,0.f,0.f,0.f};
            c = __builtin_amdgcn_mfma_f32_16x16x32_bf16(a0, wa[nt*4+0], c, 0,0,0);
            c = __builtin_amdgcn_mfma_f32_16x16x32_bf16(a1, wa[nt*4+1], c, 0,0,0);
            c = __builtin_amdgcn_mfma_f32_16x16x32_bf16(a2, wa[nt*4+2], c, 0,0,0);
            c = __builtin_amdgcn_mfma_f32_16x16x32_bf16(a3, wa[nt*4+3], c, 0,0,0);
            p[nt] = c;
        }
        f32x4 pt[4];
        #pragma unroll
        for(int nt = 0; nt < 4; nt++){
            f32x4 c = {0.f,0.f,0.f,0.f};
            c = __builtin_amdgcn_mfma_f32_16x16x32_bf16(c0, wb[nt*4+0], c, 0,0,0);
            c = __builtin_amdgcn_mfma_f32_16x16x32_bf16(c1, wb[nt*4+1], c, 0,0,0);
            c = __builtin_amdgcn_mfma_f32_16x16x32_bf16(c2, wb[nt*4+2], c, 0,0,0);
            c = __builtin_amdgcn_mfma_f32_16x16x32_bf16(c3, wb[nt*4+3], c, 0,0,0);
            pt[nt] = c;
        }
        float l0[4], l1[4];
        #pragma unroll
        for(int r = 0; r < 4; r++){
            float s0 = 0.f, s1 = 0.f;
            #pragma unroll
            for(int t = 0; t < 4; t++){
                float xp = fmaxf(p[t][r]  + b1c[t], 0.f);
                float xq = fmaxf(pt[t][r] + btc[t], 0.f);
                s0 += xp*wfp[0][t] + xq*wft[0][t];
                s1 += xp*wfp[1][t] + xq*wft[1][t];
            }
            l0[r] = s0; l1[r] = s1;
        }
        #pragma unroll
        for(int r = 0; r < 4; r++)
            #pragma unroll
            for(int msk = 1; msk < 16; msk <<= 1){
                l0[r] += __shfl_xor(l0[r], msk, 64);
                l1[r] += __shfl_xor(l1[r], msk, 64);
            }
        if(m == 0){
            #pragma unroll
            for(int r = 0; r < 4; r++){
                float a = l0[r] + bf0, b = l1[r] + bf1;
                float mx = fmaxf(a, b);
                float lse = mx + __logf(__expf(a - mx) + __expf(b - mx));
                int oi = eid[g*16 + q*4 + r];
                if(fl){
                    float2 v; v.x = a - lse; v.y = b - lse;
                    ((float2*)out)[oi] = v;
                }else{
                    u32 pack = (u32)f2bf(a - lse) | ((u32)f2bf(b - lse) << 16);
                    ((u32*)out)[oi] = pack;
                }
            }
        }
    }
}

// ---------------- workspace layout (~55.5 MB) ----------------
static const size_t O_FLAG   = 0;
static const size_t O_CANON  = 4096;       // 3,402,248
static const size_t O_GIT    = 3407872;    // 49,152
static const size_t O_W2P    = 3457024;    // 8,192
static const size_t O_WHHP   = 3465216;    // 24,576
static const size_t O_L1P    = 3489792;    // 16,384
static const size_t O_LTP    = 3506176;    // 16,384
static const size_t O_DINV   = 3522560;    // 400,000
static const size_t O_DEG    = 3922560;    // 400,000
static const size_t O_ROWPTR = 4322560;    // 400,128
static const size_t O_CURSOR = 4722688;    // 400,000
static const size_t O_BSUM   = 5122688;    // 2,048
static const size_t O_EL     = 5124736;    // 4,000,000
static const size_t O_DL     = 9125888;    // 4,000,000
static const size_t O_EID    = 13125888;   // 4,000,000
static const size_t O_SRC    = 17125888;   // N*64 bf16 = 12,800,000
static const size_t O_H1     = 29925888;   // N*64 bf16 = 12,800,000
static const size_t O_NODEF  = 29925888;   // N*128 bf16 = 25,600,000 (overlays h1: h1 dead after conv2)
// end = 55,525,888

extern "C" void kernel_launch(void* const* d_in, const int* in_sizes, int n_in,
                              void* d_out, int out_size, void* d_ws, size_t ws_size,
                              hipStream_t stream){
    const void* x    = d_in[0];
    const int*  ei   = (const int*)d_in[1];
    const int*  xt   = (const int*)d_in[2];

    char* ws = (char*)d_ws;
    int*   flagp  = (int*)(ws + O_FLAG);
    float* canon  = (float*)(ws + O_CANON);
    float* giT    = (float*)(ws + O_GIT);
    u16*   w2p    = (u16*)(ws + O_W2P);
    u16*   whhp   = (u16*)(ws + O_WHHP);
    u16*   l1p    = (u16*)(ws + O_L1P);
    u16*   ltp    = (u16*)(ws + O_LTP);
    float* dinv   = (float*)(ws + O_DINV);
    int*   deg    = (int*)(ws + O_DEG);
    int*   rowptr = (int*)(ws + O_ROWPTR);
    int*   cursor = (int*)(ws + O_CURSOR);
    int*   bsum   = (int*)(ws + O_BSUM);
    int*   el     = (int*)(ws + O_EL);
    int*   dl     = (int*)(ws + O_DL);
    int*   eid    = (int*)(ws + O_EID);
    u16*   src    = (u16*)(ws + O_SRC);
    u16*   hbuf1  = (u16*)(ws + O_H1);
    u16*   nodef  = (u16*)(ws + O_NODEF);

    // dtype detect + canonicalize
    k_detect<<<1, 256, 0, stream>>>((const u16*)x, flagp);
    k_convert<<<(CTOT+255)/256, 256, 0, stream>>>(flagp,
        x, d_in[3], d_in[4], d_in[5], d_in[6], d_in[7], d_in[8], d_in[9],
        d_in[10], d_in[11], d_in[12], d_in[13], d_in[14], d_in[15], d_in[16], d_in[17],
        canon);

    const float* cx   = canon + CX;
    const float* cw1  = canon + CW1;
    const float* cb1  = canon + CB1;
    const float* cw2  = canon + CW2;
    const float* cb2  = canon + CB2;
    const float* cemb = canon + CEMB;
    const float* cwih = canon + CWIH;
    const float* cwhh = canon + CWHH;
    const float* cbih = canon + CBIH;
    const float* cbhh = canon + CBHH;
    const float* cl1w = canon + CL1W;
    const float* cl1b = canon + CL1B;
    const float* cltw = canon + CLTW;
    const float* cltb = canon + CLTB;
    const float* clfw = canon + CLFW;
    const float* clfb = canon + CLFB;

    // CSR build (once; reused by both GCN layers and the edge kernel)
    hipMemsetAsync(deg, 0, (size_t)N_NODES*4, stream);
    k_hist <<<(N_EDGES+255)/256, 256, 0, stream>>>(ei, deg);
    k_scan1<<<NBLK, 256, 0, stream>>>(deg, rowptr, bsum);
    k_scan2<<<1, 512, 0, stream>>>(bsum);
    k_scan3<<<NBLK, 256, 0, stream>>>(deg, bsum, rowptr, cursor, dinv);
    k_fill <<<(N_EDGES+255)/256, 256, 0, stream>>>(ei, cursor, el, dl, eid);

    // weight packing + gi table (tiny)
    k_packb<<<(64*64+255)/256, 256, 0, stream>>>(cw2, w2p, 64, 64, 64, 1);
    k_packb<<<(64*192+255)/256, 256, 0, stream>>>(cwhh, whhp, 64, 192, 1, 64);
    k_packb<<<(128*64+255)/256, 256, 0, stream>>>(cl1w, l1p, 128, 64, 1, 128);
    k_packb<<<(128*64+255)/256, 256, 0, stream>>>(cltw, ltp, 128, 64, 1, 128);
    k_gitab<<<(64*192+255)/256, 256, 0, stream>>>(cemb, cwih, cbih, cbhh, giT);

    // GCN layer 1 (src -> h1, stride 64)
    k_t1s<<<N_NODES*64/256, 256, 0, stream>>>(cx, cw1, dinv, src);
    k_gather_ep<<<N_NODES*64/256, 256, 0, stream>>>(rowptr, el, src, dinv, cb1, hbuf1, 64);

    // GCN layer 2 (h1 -> src -> nodef[+0], stride 128)
    k_conv2<<<(N_NODES/16 + 3)/4, 256, 0, stream>>>(hbuf1, w2p, dinv, src);
    k_gather_ep<<<N_NODES*64/256, 256, 0, stream>>>(rowptr, el, src, dinv, cb2, nodef, 128);

    // GRU over text -> nodef[+64], stride 128
    k_gru<<<(N_NODES/16 + 3)/4, 256, 0, stream>>>(xt, whhp, giT, cbhh, nodef + 64);

    // edge-pair MLPs + final + log_softmax (CSR order, scatter by eid)
    k_edge<<<2048, 256, 0, stream>>>(el, dl, eid, nodef, l1p, ltp, cl1b, cltb, clfw, clfb,
                                     flagp, d_out);
}

// Round 8
// 523.473 us; speedup vs baseline: 1.7431x; 1.0123x over previous
//
#include <hip/hip_runtime.h>
#include <stdint.h>

#define N_NODES 100000
#define N_EDGES 1000000
#define NBLK 391   // ceil(N_NODES/256)

typedef unsigned short u16;
typedef unsigned int u32;
typedef __attribute__((ext_vector_type(8))) short bshort8;
typedef __attribute__((ext_vector_type(4))) float f32x4;

__device__ __forceinline__ float bf2f(u16 u){ union{float f; u32 i;} x; x.i=((u32)u)<<16; return x.f; }
__device__ __forceinline__ u16 f2bf(float f){ union{float f; u32 i;} x; x.f=f; u32 r = x.i + 0x7FFFu + ((x.i>>16)&1u); return (u16)(r>>16); }

__device__ __forceinline__ float fexp2(float x){
#if __has_builtin(__builtin_amdgcn_exp2f)
    return __builtin_amdgcn_exp2f(x);
#else
    return exp2f(x);
#endif
}
__device__ __forceinline__ float frcp(float x){
#if __has_builtin(__builtin_amdgcn_rcpf)
    return __builtin_amdgcn_rcpf(x);
#else
    return 1.0f/x;
#endif
}
#define LOG2E 1.442695041f

// ---------------- dtype detector (f32 vs bf16 device buffers) ----------------
__global__ void k_detect(const u16* __restrict__ x, int* flagp){
    __shared__ int cnt;
    if(threadIdx.x == 0) cnt = 0;
    __syncthreads();
    int c = 0;
    for(int i = threadIdx.x; i < 2048; i += 256){
        int e = (x[i] >> 7) & 0xFF;
        if(e >= 0x90) c++;
    }
    atomicAdd(&cnt, c);
    __syncthreads();
    if(threadIdx.x == 0) flagp[0] = (cnt > 64) ? 1 : 0;   // 1 = f32, 0 = bf16
}

// canonical f32 table offsets
#define CX    0
#define CW1   800000
#define CB1   800512
#define CW2   800576
#define CB2   804672
#define CEMB  804736
#define CWIH  808832
#define CWHH  821120
#define CBIH  833408
#define CBHH  833600
#define CL1W  833792
#define CL1B  841984
#define CLTW  842048
#define CLTB  850240
#define CLFW  850304
#define CLFB  850560
#define CTOT  850562

__device__ __forceinline__ float ldany(const void* p, int i, int fl){
    return fl ? ((const float*)p)[i] : bf2f(((const u16*)p)[i]);
}

__global__ void k_convert(const int* __restrict__ flagp,
                          const void* x, const void* w1, const void* b1, const void* w2,
                          const void* b2, const void* emb, const void* wih, const void* whh,
                          const void* bih, const void* bhh, const void* l1w, const void* l1b,
                          const void* ltw, const void* ltb, const void* lfw, const void* lfb,
                          float* __restrict__ canon){
    int i = blockIdx.x*256 + threadIdx.x;
    if(i >= CTOT) return;
    int fl = *flagp;
    const void* p; int off;
    if     (i < CW1 ){ p = x;   off = i;        }
    else if(i < CB1 ){ p = w1;  off = i - CW1;  }
    else if(i < CW2 ){ p = b1;  off = i - CB1;  }
    else if(i < CB2 ){ p = w2;  off = i - CW2;  }
    else if(i < CEMB){ p = b2;  off = i - CB2;  }
    else if(i < CWIH){ p = emb; off = i - CEMB; }
    else if(i < CWHH){ p = wih; off = i - CWIH; }
    else if(i < CBIH){ p = whh; off = i - CWHH; }
    else if(i < CBHH){ p = bih; off = i - CBIH; }
    else if(i < CL1W){ p = bhh; off = i - CBHH; }
    else if(i < CL1B){ p = l1w; off = i - CL1W; }
    else if(i < CLTW){ p = l1b; off = i - CL1B; }
    else if(i < CLTB){ p = ltw; off = i - CLTW; }
    else if(i < CLFW){ p = ltb; off = i - CLTB; }
    else if(i < CLFB){ p = lfw; off = i - CLFW; }
    else             { p = lfb; off = i - CLFB; }
    float v = ldany(p, off, fl);
    canon[i] = (v == v && fabsf(v) < 1e30f) ? v : 0.f;
}

// ---------------- CSR build: histogram -> scan -> fill (el, dl, eid) ----------------
__global__ void k_hist(const int* __restrict__ ei, int* __restrict__ deg){
    int e = blockIdx.x*256 + threadIdx.x;
    if(e < N_EDGES) atomicAdd(&deg[ei[N_EDGES + e]], 1);
}
__global__ void k_scan1(const int* __restrict__ deg, int* __restrict__ rowptr,
                        int* __restrict__ bsum){
    __shared__ int sh[256];
    int tid = threadIdx.x;
    int i = blockIdx.x*256 + tid;
    int v = (i < N_NODES) ? deg[i] : 0;
    sh[tid] = v;
    __syncthreads();
    for(int off = 1; off < 256; off <<= 1){
        int t = (tid >= off) ? sh[tid - off] : 0;
        __syncthreads();
        sh[tid] += t;
        __syncthreads();
    }
    if(i < N_NODES) rowptr[i] = sh[tid] - v;
    if(tid == 255) bsum[blockIdx.x] = sh[255];
}
__global__ void k_scan2(int* __restrict__ bsum){
    __shared__ int sh[512];
    int tid = threadIdx.x;
    int v = (tid < NBLK) ? bsum[tid] : 0;
    sh[tid] = v;
    __syncthreads();
    for(int off = 1; off < 512; off <<= 1){
        int t = (tid >= off) ? sh[tid - off] : 0;
        __syncthreads();
        sh[tid] += t;
        __syncthreads();
    }
    if(tid < NBLK) bsum[tid] = sh[tid] - v;
}
__global__ void k_scan3(const int* __restrict__ deg, const int* __restrict__ bsum,
                        int* __restrict__ rowptr, int* __restrict__ cursor,
                        float* __restrict__ dinv){
    int i = blockIdx.x*256 + threadIdx.x;
    if(i < N_NODES){
        int r = rowptr[i] + bsum[i >> 8];
        rowptr[i] = r;
        cursor[i] = r;
        dinv[i] = rsqrtf((float)deg[i] + 1.0f);   // +1 self loop
    }
    if(i == 0) rowptr[N_NODES] = N_EDGES;
}
__global__ void k_fill(const int* __restrict__ ei, int* __restrict__ cursor,
                       int* __restrict__ el, int* __restrict__ dl, int* __restrict__ eid){
    int e = blockIdx.x*256 + threadIdx.x;
    if(e < N_EDGES){
        int s = ei[e], d = ei[N_EDGES + e];
        int pos = atomicAdd(&cursor[d], 1);
        el[pos] = s;
        dl[pos] = d;
        eid[pos] = e;
    }
}

// ---------------- conv1: src = bf16((x @ W1) * dinv) ----------------
__global__ void k_t1s(const float* __restrict__ cx, const float* __restrict__ cw1,
                      const float* __restrict__ dinv, u16* __restrict__ src){
    __shared__ float w[512];
    int t = threadIdx.x;
    w[t]       = cw1[t];
    w[t + 256] = cw1[t + 256];
    __syncthreads();
    int i = blockIdx.x*256 + t;      // grid exactly N*64/256
    int n = i >> 6, f = i & 63;
    const float* xr = cx + n*8;
    float acc = 0.f;
    #pragma unroll
    for(int k = 0; k < 8; k++) acc += xr[k] * w[k*64 + f];
    src[i] = f2bf(acc * dinv[n]);
}

// ---------------- fused gather + epilogue (bf16 src rows, strided bf16 out) ----------------
__global__ __launch_bounds__(256)
void k_gather_ep(const int* __restrict__ rowptr, const int* __restrict__ el,
                 const u16* __restrict__ src, const float* __restrict__ dinv,
                 const float* __restrict__ b, u16* __restrict__ h, int ostride){
    int gid = blockIdx.x*256 + threadIdx.x;   // grid exactly N*64/256
    int node = gid >> 6, lane = gid & 63;
    int beg = rowptr[node], end = rowptr[node + 1];
    float acc = bf2f(src[node*64 + lane]);    // self loop (pre-scaled by dinv[src])
    int i = beg;
    for(; i + 4 <= end; i += 4){
        int s0 = el[i], s1 = el[i+1], s2 = el[i+2], s3 = el[i+3];
        float a0 = bf2f(src[s0*64 + lane]);
        float a1 = bf2f(src[s1*64 + lane]);
        float a2 = bf2f(src[s2*64 + lane]);
        float a3 = bf2f(src[s3*64 + lane]);
        acc += a0; acc += a1; acc += a2; acc += a3;
    }
    for(; i < end; i++) acc += bf2f(src[el[i]*64 + lane]);
    h[node*ostride + lane] = f2bf(fmaxf(dinv[node]*acc + b[lane], 0.f));
}

// ---------------- pack B matrix (f32 canon -> bf16 MFMA fragment order) ----------------
__global__ void k_packb(const float* __restrict__ src, u16* __restrict__ dst,
                        int K, int N, int ldk, int ldn){
    int i = blockIdx.x*256 + threadIdx.x;
    if(i >= K*N) return;
    int k = i / N, n = i % N;
    int kt = k >> 5, kk = k & 31, q = kk >> 3, j = kk & 7;
    int nt = n >> 4, nn = n & 15;
    int KT = K >> 5;
    dst[(((nt*KT + kt)*64) + (q*16 + nn))*8 + j] = f2bf(src[k*ldk + n*ldn]);
}

// ---------------- gi table (b_hh folded for r,z) ----------------
__global__ void k_gitab(const float* __restrict__ emb, const float* __restrict__ wih,
                        const float* __restrict__ bih, const float* __restrict__ bhh,
                        float* __restrict__ giT){
    int i = blockIdx.x*256 + threadIdx.x;
    if(i >= 64*192) return;
    int v = i / 192, g = i % 192;
    float acc = bih[g] + ((g < 128) ? bhh[g] : 0.0f);
    const float* wr = wih + g*64;
    const float* er = emb + v*64;
    for(int f = 0; f < 64; f++) acc += wr[f] * er[f];
    giT[i] = acc;
}

// ---------------- conv2 GEMM: src = bf16((h1 @ W2) * dinv) ----------------
__global__ __launch_bounds__(256, 4)
void k_conv2(const u16* __restrict__ h, const u16* __restrict__ w2p,
             const float* __restrict__ dinv, u16* __restrict__ src){
    int wv = threadIdx.x >> 6, lane = threadIdx.x & 63;
    int g = blockIdx.x*4 + wv;
    if(g >= N_NODES/16) return;
    int q = lane >> 4, m = lane & 15, col = m;
    bshort8 a0 = *(const bshort8*)(h + (g*16 + m)*64 + q*8);
    bshort8 a1 = *(const bshort8*)(h + (g*16 + m)*64 + 32 + q*8);
    f32x4 acc[4];
    #pragma unroll
    for(int nt = 0; nt < 4; nt++){
        f32x4 c = {0.f,0.f,0.f,0.f};
        c = __builtin_amdgcn_mfma_f32_16x16x32_bf16(a0, *(const bshort8*)(w2p + ((nt*2+0)*64 + lane)*8), c, 0,0,0);
        c = __builtin_amdgcn_mfma_f32_16x16x32_bf16(a1, *(const bshort8*)(w2p + ((nt*2+1)*64 + lane)*8), c, 0,0,0);
        acc[nt] = c;
    }
    #pragma unroll
    for(int nt = 0; nt < 4; nt++)
        #pragma unroll
        for(int r = 0; r < 4; r++){
            int node = g*16 + q*4 + r;
            src[node*64 + nt*16 + col] = f2bf(acc[nt][r] * dinv[node]);
        }
}

// ---------------- GRU: wave per 16 nodes; Whh in LDS; strided output into nodef ----------------
__global__ __launch_bounds__(256, 3)
void k_gru(const int* __restrict__ xt, const u16* __restrict__ whhp,
           const float* __restrict__ giT, const float* __restrict__ bhh,
           u16* __restrict__ txt){   // txt = nodef + 64, stride 128
    __shared__ __align__(16) u16 wsh[12288];
    __shared__ __align__(16) float hsh[4][16][68];
    int tid = threadIdx.x;
    {
        const uint4* s = (const uint4*)whhp;
        uint4* d = (uint4*)wsh;
        #pragma unroll
        for(int i = 0; i < 6; i++) d[tid + 256*i] = s[tid + 256*i];
    }
    __syncthreads();

    int wv = tid >> 6, lane = tid & 63;
    int q = lane >> 4, m = lane & 15, col = m;
    int g = blockIdx.x*4 + wv;
    bool active = g < (N_NODES/16);
    int nb = active ? g*16 : 0;

    float bhhn[4];
    #pragma unroll
    for(int t = 0; t < 4; t++) bhhn[t] = bhh[128 + t*16 + col];

    const bshort8* wl = (const bshort8*)wsh;
    float* hp = &hsh[wv][m][0];

    float hc[4][4];
    #pragma unroll
    for(int t = 0; t < 4; t++)
        #pragma unroll
        for(int r = 0; r < 4; r++) hc[t][r] = 0.f;

    for(int s = 0; s < 10; s++){
        #pragma unroll
        for(int t = 0; t < 4; t++)
            #pragma unroll
            for(int r = 0; r < 4; r++)
                hsh[wv][q*4 + r][t*16 + col] = hc[t][r];

        asm volatile("" ::: "memory");
        float4 x0 = *(float4*)(hp + q*8);
        float4 x1 = *(float4*)(hp + q*8 + 4);
        float4 x2 = *(float4*)(hp + 32 + q*8);
        float4 x3 = *(float4*)(hp + 32 + q*8 + 4);
        u32 aw[8];
        aw[0] = (u32)f2bf(x0.x) | ((u32)f2bf(x0.y) << 16);
        aw[1] = (u32)f2bf(x0.z) | ((u32)f2bf(x0.w) << 16);
        aw[2] = (u32)f2bf(x1.x) | ((u32)f2bf(x1.y) << 16);
        aw[3] = (u32)f2bf(x1.z) | ((u32)f2bf(x1.w) << 16);
        aw[4] = (u32)f2bf(x2.x) | ((u32)f2bf(x2.y) << 16);
        aw[5] = (u32)f2bf(x2.z) | ((u32)f2bf(x2.w) << 16);
        aw[6] = (u32)f2bf(x3.x) | ((u32)f2bf(x3.y) << 16);
        aw[7] = (u32)f2bf(x3.z) | ((u32)f2bf(x3.w) << 16);
        bshort8 a0 = *(bshort8*)&aw[0];
        bshort8 a1 = *(bshort8*)&aw[4];

        int tok[4];
        #pragma unroll
        for(int r = 0; r < 4; r++) tok[r] = xt[(nb + q*4 + r)*10 + s] & 63;

        f32x4 acc[12];
        #pragma unroll
        for(int nt = 0; nt < 12; nt++){
            f32x4 c = {0.f,0.f,0.f,0.f};
            c = __builtin_amdgcn_mfma_f32_16x16x32_bf16(a0, wl[(nt*2+0)*64 + lane], c, 0,0,0);
            c = __builtin_amdgcn_mfma_f32_16x16x32_bf16(a1, wl[(nt*2+1)*64 + lane], c, 0,0,0);
            acc[nt] = c;
        }

        #pragma unroll
        for(int r = 0; r < 4; r++){
            const float* gp = giT + tok[r]*192 + col;
            #pragma unroll
            for(int t = 0; t < 4; t++){
                float gir = gp[t*16], giz = gp[64 + t*16], gin = gp[128 + t*16];
                float rr = frcp(1.0f + fexp2(-LOG2E*(gir + acc[t][r])));
                float zz = frcp(1.0f + fexp2(-LOG2E*(giz + acc[4+t][r])));
                float narg = gin + rr*(acc[8+t][r] + bhhn[t]);
                float e2 = fexp2(2.0f*LOG2E*narg);
                float nn = 1.0f - 2.0f*frcp(e2 + 1.0f);
                hc[t][r] = nn + zz*(hc[t][r] - nn);
            }
        }
        asm volatile("" ::: "memory");
    }
    if(active){
        #pragma unroll
        for(int t = 0; t < 4; t++)
            #pragma unroll
            for(int r = 0; r < 4; r++)
                txt[(size_t)(nb + q*4 + r)*128 + t*16 + col] = f2bf(hc[t][r]);
    }
}

// ---------------- edge MLP: cooperative row staging through LDS ----------------
// Per 16-edge iteration a wave stages 32 node-rows (256 B each) with 16
// contiguous lanes/row (16 B/lane) -> ~32 sequential 256-B segments instead of
// 128 scattered 64-B segments. R7 NaN fix: uniform uint4 LDS access type +
// asm memory clobbers bounding the read window (TBAA reorder hazard).
__global__ __launch_bounds__(256, 2)
void k_edge(const int* __restrict__ el, const int* __restrict__ dl, const int* __restrict__ eid,
            const u16* __restrict__ nodef,   // [N][128]: h2 at +0, txt at +64
            const u16* __restrict__ l1p, const u16* __restrict__ ltp,
            const float* __restrict__ b1, const float* __restrict__ bt,
            const float* __restrict__ wfin, const float* __restrict__ bfin,
            const int* __restrict__ flagp, void* __restrict__ out){
    // rows 0..15: s-rows; rows 16..31: d-rows. Row stride 136 u16 = 272 B
    // (17 x 16 B): uniform bank spread for writes and reads.
    __shared__ __align__(16) u16 esh[4][32][136];
    union U4B8 { uint4 u; bshort8 b; };
    int tid = threadIdx.x;
    int wv = tid >> 6, lane = tid & 63;
    int q = lane >> 4, m = lane & 15, col = m;
    int t16 = lane & 15;     // 16-B chunk index within a row (staging)
    int rq  = lane >> 4;     // row-within-group (staging)
    int wgid = (blockIdx.x*256 + tid) >> 6;
    int nw = (gridDim.x*256) >> 6;
    int fl = *flagp;

    bshort8 wa[16], wb[16];
    #pragma unroll
    for(int i = 0; i < 16; i++){
        wa[i] = *(const bshort8*)(l1p + (i*64 + lane)*8);
        wb[i] = *(const bshort8*)(ltp + (i*64 + lane)*8);
    }
    float b1c[4], btc[4], wfp[2][4], wft[2][4];
    #pragma unroll
    for(int t = 0; t < 4; t++){
        b1c[t] = b1[t*16 + col];
        btc[t] = bt[t*16 + col];
        wfp[0][t] = wfin[t*16 + col];        wfp[1][t] = wfin[128 + t*16 + col];
        wft[0][t] = wfin[64 + t*16 + col];   wft[1][t] = wfin[128 + 64 + t*16 + col];
    }
    float bf0 = bfin[0], bf1 = bfin[1];

    for(int g = wgid; g < N_EDGES/16; g += nw){
        int pos = g*16 + m;
        int s = el[pos], d = dl[pos];

        // ---- cooperative staging: 8 steps x 4 rows x 256 B ----
        #pragma unroll
        for(int step = 0; step < 8; step++){
            int r = step*4 + rq;                 // 0..31
            int edge = r & 15;
            int nodeS = __shfl(s, edge, 16);
            int nodeD = __shfl(d, edge, 16);
            int node = (r < 16) ? nodeS : nodeD;
            const uint4* gp = (const uint4*)(nodef + (size_t)node*128 + t16*8);
            *(uint4*)&esh[wv][r][t16*8] = *gp;
        }
        asm volatile("" ::: "memory");   // ds_writes complete (program order) before reads

        const u16* sr = &esh[wv][m][0];
        const u16* dr = &esh[wv][16 + m][0];
        U4B8 a0u, a1u, a2u, a3u, c0u, c1u, c2u, c3u;
        a0u.u = *(const uint4*)(sr + q*8);
        a1u.u = *(const uint4*)(sr + 32 + q*8);
        a2u.u = *(const uint4*)(dr + q*8);
        a3u.u = *(const uint4*)(dr + 32 + q*8);
        c0u.u = *(const uint4*)(sr + 64 + q*8);
        c1u.u = *(const uint4*)(sr + 96 + q*8);
        c2u.u = *(const uint4*)(dr + 64 + q*8);
        c3u.u = *(const uint4*)(dr + 96 + q*8);

        f32x4 p[4];
        #pragma unroll
        for(int nt = 0; nt < 4; nt++){
            f32x4 c = {0.f,0.f,0.f,0.f};
            c = __builtin_amdgcn_mfma_f32_16x16x32_bf16(a0u.b, wa[nt*4+0], c, 0,0,0);
            c = __builtin_amdgcn_mfma_f32_16x16x32_bf16(a1u.b, wa[nt*4+1], c, 0,0,0);
            c = __builtin_amdgcn_mfma_f32_16x16x32_bf16(a2u.b, wa[nt*4+2], c, 0,0,0);
            c = __builtin_amdgcn_mfma_f32_16x16x32_bf16(a3u.b, wa[nt*4+3], c, 0,0,0);
            p[nt] = c;
        }
        f32x4 pt[4];
        #pragma unroll
        for(int nt = 0; nt < 4; nt++){
            f32x4 c = {0.f,0.f,0.f,0.f};
            c = __builtin_amdgcn_mfma_f32_16x16x32_bf16(c0u.b, wb[nt*4+0], c, 0,0,0);
            c = __builtin_amdgcn_mfma_f32_16x16x32_bf16(c1u.b, wb[nt*4+1], c, 0,0,0);
            c = __builtin_amdgcn_mfma_f32_16x16x32_bf16(c2u.b, wb[nt*4+2], c, 0,0,0);
            c = __builtin_amdgcn_mfma_f32_16x16x32_bf16(c3u.b, wb[nt*4+3], c, 0,0,0);
            pt[nt] = c;
        }
        float l0[4], l1[4];
        #pragma unroll
        for(int r = 0; r < 4; r++){
            float s0 = 0.f, s1 = 0.f;
            #pragma unroll
            for(int t = 0; t < 4; t++){
                float xp = fmaxf(p[t][r]  + b1c[t], 0.f);
                float xq = fmaxf(pt[t][r] + btc[t], 0.f);
                s0 += xp*wfp[0][t] + xq*wft[0][t];
                s1 += xp*wfp[1][t] + xq*wft[1][t];
            }
            l0[r] = s0; l1[r] = s1;
        }
        #pragma unroll
        for(int r = 0; r < 4; r++)
            #pragma unroll
            for(int msk = 1; msk < 16; msk <<= 1){
                l0[r] += __shfl_xor(l0[r], msk, 64);
                l1[r] += __shfl_xor(l1[r], msk, 64);
            }
        if(m == 0){
            #pragma unroll
            for(int r = 0; r < 4; r++){
                float a = l0[r] + bf0, b = l1[r] + bf1;
                float mx = fmaxf(a, b);
                float lse = mx + __logf(__expf(a - mx) + __expf(b - mx));
                int oi = eid[g*16 + q*4 + r];
                if(fl){
                    float2 v; v.x = a - lse; v.y = b - lse;
                    ((float2*)out)[oi] = v;
                }else{
                    u32 pack = (u32)f2bf(a - lse) | ((u32)f2bf(b - lse) << 16);
                    ((u32*)out)[oi] = pack;
                }
            }
        }
        asm volatile("" ::: "memory");   // reads done before next iteration's staging
    }
}

// ---------------- workspace layout (~55.5 MB) ----------------
static const size_t O_FLAG   = 0;
static const size_t O_CANON  = 4096;       // 3,402,248
static const size_t O_GIT    = 3407872;    // 49,152
static const size_t O_W2P    = 3457024;    // 8,192
static const size_t O_WHHP   = 3465216;    // 24,576
static const size_t O_L1P    = 3489792;    // 16,384
static const size_t O_LTP    = 3506176;    // 16,384
static const size_t O_DINV   = 3522560;    // 400,000
static const size_t O_DEG    = 3922560;    // 400,000
static const size_t O_ROWPTR = 4322560;    // 400,128
static const size_t O_CURSOR = 4722688;    // 400,000
static const size_t O_BSUM   = 5122688;    // 2,048
static const size_t O_EL     = 5124736;    // 4,000,000
static const size_t O_DL     = 9125888;    // 4,000,000
static const size_t O_EID    = 13125888;   // 4,000,000
static const size_t O_SRC    = 17125888;   // N*64 bf16 = 12,800,000
static const size_t O_H1     = 29925888;   // N*64 bf16 = 12,800,000
static const size_t O_NODEF  = 29925888;   // N*128 bf16 = 25,600,000 (overlays h1: h1 dead after conv2)
// end = 55,525,888

extern "C" void kernel_launch(void* const* d_in, const int* in_sizes, int n_in,
                              void* d_out, int out_size, void* d_ws, size_t ws_size,
                              hipStream_t stream){
    const void* x    = d_in[0];
    const int*  ei   = (const int*)d_in[1];
    const int*  xt   = (const int*)d_in[2];

    char* ws = (char*)d_ws;
    int*   flagp  = (int*)(ws + O_FLAG);
    float* canon  = (float*)(ws + O_CANON);
    float* giT    = (float*)(ws + O_GIT);
    u16*   w2p    = (u16*)(ws + O_W2P);
    u16*   whhp   = (u16*)(ws + O_WHHP);
    u16*   l1p    = (u16*)(ws + O_L1P);
    u16*   ltp    = (u16*)(ws + O_LTP);
    float* dinv   = (float*)(ws + O_DINV);
    int*   deg    = (int*)(ws + O_DEG);
    int*   rowptr = (int*)(ws + O_ROWPTR);
    int*   cursor = (int*)(ws + O_CURSOR);
    int*   bsum   = (int*)(ws + O_BSUM);
    int*   el     = (int*)(ws + O_EL);
    int*   dl     = (int*)(ws + O_DL);
    int*   eid    = (int*)(ws + O_EID);
    u16*   src    = (u16*)(ws + O_SRC);
    u16*   hbuf1  = (u16*)(ws + O_H1);
    u16*   nodef  = (u16*)(ws + O_NODEF);

    // dtype detect + canonicalize
    k_detect<<<1, 256, 0, stream>>>((const u16*)x, flagp);
    k_convert<<<(CTOT+255)/256, 256, 0, stream>>>(flagp,
        x, d_in[3], d_in[4], d_in[5], d_in[6], d_in[7], d_in[8], d_in[9],
        d_in[10], d_in[11], d_in[12], d_in[13], d_in[14], d_in[15], d_in[16], d_in[17],
        canon);

    const float* cx   = canon + CX;
    const float* cw1  = canon + CW1;
    const float* cb1  = canon + CB1;
    const float* cw2  = canon + CW2;
    const float* cb2  = canon + CB2;
    const float* cemb = canon + CEMB;
    const float* cwih = canon + CWIH;
    const float* cwhh = canon + CWHH;
    const float* cbih = canon + CBIH;
    const float* cbhh = canon + CBHH;
    const float* cl1w = canon + CL1W;
    const float* cl1b = canon + CL1B;
    const float* cltw = canon + CLTW;
    const float* cltb = canon + CLTB;
    const float* clfw = canon + CLFW;
    const float* clfb = canon + CLFB;

    // CSR build (once; reused by both GCN layers and the edge kernel)
    hipMemsetAsync(deg, 0, (size_t)N_NODES*4, stream);
    k_hist <<<(N_EDGES+255)/256, 256, 0, stream>>>(ei, deg);
    k_scan1<<<NBLK, 256, 0, stream>>>(deg, rowptr, bsum);
    k_scan2<<<1, 512, 0, stream>>>(bsum);
    k_scan3<<<NBLK, 256, 0, stream>>>(deg, bsum, rowptr, cursor, dinv);
    k_fill <<<(N_EDGES+255)/256, 256, 0, stream>>>(ei, cursor, el, dl, eid);

    // weight packing + gi table (tiny)
    k_packb<<<(64*64+255)/256, 256, 0, stream>>>(cw2, w2p, 64, 64, 64, 1);
    k_packb<<<(64*192+255)/256, 256, 0, stream>>>(cwhh, whhp, 64, 192, 1, 64);
    k_packb<<<(128*64+255)/256, 256, 0, stream>>>(cl1w, l1p, 128, 64, 1, 128);
    k_packb<<<(128*64+255)/256, 256, 0, stream>>>(cltw, ltp, 128, 64, 1, 128);
    k_gitab<<<(64*192+255)/256, 256, 0, stream>>>(cemb, cwih, cbih, cbhh, giT);

    // GCN layer 1 (src -> h1, stride 64)
    k_t1s<<<N_NODES*64/256, 256, 0, stream>>>(cx, cw1, dinv, src);
    k_gather_ep<<<N_NODES*64/256, 256, 0, stream>>>(rowptr, el, src, dinv, cb1, hbuf1, 64);

    // GCN layer 2 (h1 -> src -> nodef[+0], stride 128)
    k_conv2<<<(N_NODES/16 + 3)/4, 256, 0, stream>>>(hbuf1, w2p, dinv, src);
    k_gather_ep<<<N_NODES*64/256, 256, 0, stream>>>(rowptr, el, src, dinv, cb2, nodef, 128);

    // GRU over text -> nodef[+64], stride 128
    k_gru<<<(N_NODES/16 + 3)/4, 256, 0, stream>>>(xt, whhp, giT, cbhh, nodef + 64);

    // edge-pair MLPs + final + log_softmax (CSR order, scatter by eid)
    k_edge<<<2048, 256, 0, stream>>>(el, dl, eid, nodef, l1p, ltp, cl1b, cltb, clfw, clfb,
                                     flagp, d_out);
}